// Round 6
// baseline (1333.798 us; speedup 1.0000x reference)
//
#include <hip/hip_runtime.h>
#include <stdint.h>

#define NB 8
#define NN 4096
#define NC 64
#define NS 1024
#define NK 32
#define NQ (NB*NS)        /* 8192 queries */
#define NP (NQ*NK)        /* 262144 positions */
#define EPSBN 1e-5f

typedef unsigned long long u64;
typedef unsigned short u16;
typedef float v2f __attribute__((ext_vector_type(2)));
typedef short bf8_t __attribute__((ext_vector_type(8)));    // 8 bf16 (4 VGPRs)
typedef float f4_t __attribute__((ext_vector_type(4)));     // MFMA acc

__device__ __forceinline__ float lrelu(float x){ return x >= 0.0f ? x : 0.1f*x; }

__device__ __forceinline__ unsigned int fkey(float d){
    unsigned int fb = __float_as_uint(d);
    return (fb & 0x80000000u) ? ~fb : (fb | 0x80000000u);
}
// f32 -> bf16 RNE
__device__ __forceinline__ unsigned f2bf(float f){
    unsigned u = __float_as_uint(f);
    return (u + 0x7fffu + ((u >> 16) & 1u)) >> 16;
}
__device__ __forceinline__ float bflo(unsigned u){ return __uint_as_float(u << 16); }
__device__ __forceinline__ float bfhi(unsigned u){ return __uint_as_float(u & 0xffff0000u); }

// inclusive prefix-sum over 64 lanes (ints)
__device__ __forceinline__ int wave_incl_add(int x){
    int v = x;
    {int o=__builtin_amdgcn_update_dpp(0,v,0x111,0xf,0xf,true); v+=o;}
    {int o=__builtin_amdgcn_update_dpp(0,v,0x112,0xf,0xf,true); v+=o;}
    {int o=__builtin_amdgcn_update_dpp(0,v,0x114,0xf,0xf,true); v+=o;}
    {int o=__builtin_amdgcn_update_dpp(0,v,0x118,0xf,0xf,true); v+=o;}
    {int o=__builtin_amdgcn_update_dpp(0,v,0x142,0xa,0xf,true); v+=o;}
    {int o=__builtin_amdgcn_update_dpp(0,v,0x143,0xc,0xf,true); v+=o;}
    return v;
}
// sum within each 16-lane row; valid at lane%16==15
__device__ __forceinline__ float row_sum16(float x){
    int v = __float_as_int(x);
    {int o=__builtin_amdgcn_update_dpp(0,v,0x111,0xf,0xf,true); v=__float_as_int(__int_as_float(v)+__int_as_float(o));}
    {int o=__builtin_amdgcn_update_dpp(0,v,0x112,0xf,0xf,true); v=__float_as_int(__int_as_float(v)+__int_as_float(o));}
    {int o=__builtin_amdgcn_update_dpp(0,v,0x114,0xf,0xf,true); v=__float_as_int(__int_as_float(v)+__int_as_float(o));}
    {int o=__builtin_amdgcn_update_dpp(0,v,0x118,0xf,0xf,true); v=__float_as_int(__int_as_float(v)+__int_as_float(o));}
    return __int_as_float(v);
}
// max-reduce of a packed positive double across the wave, via DPP pairs
__device__ __forceinline__ double wave_max_d(double x){
    int lo = __double2loint(x), hi = __double2hiint(x);
    #define FPS_STG(ctl) { \
        int nl=__builtin_amdgcn_update_dpp(lo,lo,ctl,0xf,0xf,false); \
        int nh=__builtin_amdgcn_update_dpp(hi,hi,ctl,0xf,0xf,false); \
        double mx=fmax(__hiloint2double(hi,lo), __hiloint2double(nh,nl)); \
        lo=__double2loint(mx); hi=__double2hiint(mx); }
    FPS_STG(0x111) FPS_STG(0x112) FPS_STG(0x114) FPS_STG(0x118) FPS_STG(0x142) FPS_STG(0x143)
    #undef FPS_STG
    int flo = __builtin_amdgcn_readlane(lo, 63);
    int fhi = __builtin_amdgcn_readlane(hi, 63);
    return __hiloint2double(fhi, flo);
}

// ---------------------------------------------------------------------------
// FPS r6: TWO batches per block (4 blocks), phases interleaved so batch B's
// ~700-cyc update fills batch A's reduce/barrier/tail stalls (was ~40% of
// each 1200-cyc step on the 1-batch version). ONE barrier per step serves
// both batches. Per-batch math is byte-identical to the 511us r5 version:
// rn ops, ((dx2+dy2)+dz2), min, first-occurrence, packed f64 key, DPP
// reduce, 4 LDS slots, parity double-buffer.
// A/B LESSONS (do not redo): fmax tree+float4 LDS regressed (+20us, 30K
// conflicts); 512thr x 8pts = 571us; r4 per-block __threadfence = +650us.
// Piggybacks on the idle CUs (validated free):
//   blocks 4..515:   features f32->bf16
//   blocks 516..520: weight A-frag pack
// ---------------------------------------------------------------------------
__global__ __launch_bounds__(256,1) void fps_kernel(const float* __restrict__ xyz,
    float* __restrict__ out0, float* __restrict__ nxyz,
    const float* __restrict__ features, u16* __restrict__ fbf,
    const float* __restrict__ w0, const float* __restrict__ w1,
    const float* __restrict__ w2, const float* __restrict__ w3,
    const float* __restrict__ w4, u16* __restrict__ bwt)
{
    if (blockIdx.x >= 4 + 512){
        // weight pack (5 blocks)
        const int wb = blockIdx.x - (4 + 512);
        const float* s;
        switch (wb){
            case 0: s = w0; break; case 1: s = w1; break; case 2: s = w2; break;
            case 3: s = w3; break; default: s = w4; break;
        }
        u16* d = bwt + (size_t)wb*4096;
        for (int i = threadIdx.x; i < 4096; i += 256){
            const int f = i >> 9, lane = (i >> 3) & 63, j = i & 7;
            const int mt = f >> 1, h = f & 1;
            const int o = mt*16 + (lane & 15);
            const int c = h*32 + (lane >> 4)*8 + j;
            d[i] = (u16)f2bf(s[o*64 + c]);
        }
        return;
    }
    if (blockIdx.x >= 4){
        // feature pre-conversion: 2M floats -> bf16
        const int cb = blockIdx.x - 4;
        const float4* src = (const float4*)features;
        uint2* dst = (uint2*)fbf;
        for (int i = cb*256 + threadIdx.x; i < NB*NN*NC/4; i += 512*256){
            float4 v = src[i];
            uint2 pk;
            pk.x = f2bf(v.x) | (f2bf(v.y) << 16);
            pk.y = f2bf(v.z) | (f2bf(v.w) << 16);
            dst[i] = pk;
        }
        return;
    }
    __shared__ float sXA[NN], sYA[NN], sZA[NN];
    __shared__ float sXB[NN], sYB[NN], sZB[NN];
    __shared__ double slotsA[2][4], slotsB[2][4];
    __shared__ int sFarA[NS], sFarB[NS];
    const int t = threadIdx.x;
    const int lane = t & 63, wv = t >> 6;
    const int bA = blockIdx.x*2, bB = bA + 1;
    const float* baseA = xyz + (size_t)bA*NN*3;
    const float* baseB = xyz + (size_t)bB*NN*3;
    for (int i = t; i < NN; i += 256){
        const float* pa = baseA + 3*i;
        sXA[i] = pa[0]; sYA[i] = pa[1]; sZA[i] = pa[2];
        const float* pb_ = baseB + 3*i;
        sXB[i] = pb_[0]; sYB[i] = pb_[1]; sZB[i] = pb_[2];
    }
    __syncthreads();
    v2f PXA[8], PYA[8], PZA[8], DA[8];
    v2f PXB[8], PYB[8], PZB[8], DB[8];
    int LO[16];
    const int pb = t*16;
    #pragma unroll
    for (int j = 0; j < 8; ++j){
        PXA[j] = (v2f){ sXA[pb+2*j], sXA[pb+2*j+1] };
        PYA[j] = (v2f){ sYA[pb+2*j], sYA[pb+2*j+1] };
        PZA[j] = (v2f){ sZA[pb+2*j], sZA[pb+2*j+1] };
        DA[j]  = (v2f){ 1e10f, 1e10f };
        PXB[j] = (v2f){ sXB[pb+2*j], sXB[pb+2*j+1] };
        PYB[j] = (v2f){ sYB[pb+2*j], sYB[pb+2*j+1] };
        PZB[j] = (v2f){ sZB[pb+2*j], sZB[pb+2*j+1] };
        DB[j]  = (v2f){ 1e10f, 1e10f };
    }
    #pragma unroll
    for (int j = 0; j < 16; ++j) LO[j] = (int)(~(unsigned)(pb + j));
    int farA = 0, farB = 0;
    float cxA = sXA[0], cyA = sYA[0], czA = sZA[0];
    float cxB = sXB[0], cyB = sYB[0], czB = sZB[0];
    for (int s = 0; s < NS; ++s){
        if (t == 255){ sFarA[s] = farA; sFarB[s] = farB; }
        const int par = s & 1;
        // ---- batch A: update + wave reduce + slot write ----
        {
            double best;
            {
                #pragma clang fp contract(off)
                v2f cx2 = (v2f){cxA, cxA}, cy2 = (v2f){cyA, cyA}, cz2 = (v2f){czA, czA};
                best = -1.0;
                #pragma unroll
                for (int j = 0; j < 8; ++j){
                    v2f dx = PXA[j] - cx2;
                    v2f dy = PYA[j] - cy2;
                    v2f dz = PZA[j] - cz2;
                    v2f dd = (dx*dx + dy*dy) + dz*dz;
                    v2f nd = __builtin_elementwise_min(DA[j], dd);
                    DA[j] = nd;
                    best = fmax(best, __hiloint2double(__float_as_int(nd.x), LO[2*j]));
                    best = fmax(best, __hiloint2double(__float_as_int(nd.y), LO[2*j+1]));
                }
            }
            double wb = wave_max_d(best);
            if (lane == 0) slotsA[par][wv] = wb;
        }
        // ---- batch B: update + wave reduce + slot write (fills A's latency) ----
        {
            double best;
            {
                #pragma clang fp contract(off)
                v2f cx2 = (v2f){cxB, cxB}, cy2 = (v2f){cyB, cyB}, cz2 = (v2f){czB, czB};
                best = -1.0;
                #pragma unroll
                for (int j = 0; j < 8; ++j){
                    v2f dx = PXB[j] - cx2;
                    v2f dy = PYB[j] - cy2;
                    v2f dz = PZB[j] - cz2;
                    v2f dd = (dx*dx + dy*dy) + dz*dz;
                    v2f nd = __builtin_elementwise_min(DB[j], dd);
                    DB[j] = nd;
                    best = fmax(best, __hiloint2double(__float_as_int(nd.x), LO[2*j]));
                    best = fmax(best, __hiloint2double(__float_as_int(nd.y), LO[2*j+1]));
                }
            }
            double wb = wave_max_d(best);
            if (lane == 0) slotsB[par][wv] = wb;
        }
        __syncthreads();   // one barrier serves both batches
        // ---- tails (independent; LDS reads overlap) ----
        {
            double s0 = slotsA[par][0], s1 = slotsA[par][1];
            double s2 = slotsA[par][2], s3 = slotsA[par][3];
            double mm = fmax(fmax(s0, s1), fmax(s2, s3));
            farA = (int)(~(unsigned)__double2loint(mm));
            cxA = sXA[farA]; cyA = sYA[farA]; czA = sZA[farA];
        }
        {
            double s0 = slotsB[par][0], s1 = slotsB[par][1];
            double s2 = slotsB[par][2], s3 = slotsB[par][3];
            double mm = fmax(fmax(s0, s1), fmax(s2, s3));
            farB = (int)(~(unsigned)__double2loint(mm));
            cxB = sXB[farB]; cyB = sYB[farB]; czB = sZB[farB];
        }
    }
    __syncthreads();
    for (int s = t; s < NS; s += 256){
        const int fA = sFarA[s];
        const float xA = sXA[fA], yA = sYA[fA], zA = sZA[fA];
        float* npqA = nxyz + ((size_t)bA*NS + s)*3;
        npqA[0]=xA; npqA[1]=yA; npqA[2]=zA;
        out0[(bA*3+0)*NS+s]=xA; out0[(bA*3+1)*NS+s]=yA; out0[(bA*3+2)*NS+s]=zA;
        const int fB = sFarB[s];
        const float xB = sXB[fB], yB = sYB[fB], zB = sZB[fB];
        float* npqB = nxyz + ((size_t)bB*NS + s)*3;
        npqB[0]=xB; npqB[1]=yB; npqB[2]=zB;
        out0[(bB*3+0)*NS+s]=xB; out0[(bB*3+1)*NS+s]=yB; out0[(bB*3+2)*NS+s]=zB;
    }
}

// ---------------------------------------------------------------------------
// KNN (unchanged): exact 32nd-smallest via bitwise binary search on fkey.
// ---------------------------------------------------------------------------
__global__ __launch_bounds__(256,2) void knn_kernel(const float* __restrict__ xyz,
                                                    const float* __restrict__ nxyz,
                                                    int* __restrict__ kidx)
{
    const int t = threadIdx.x, lane = t & 63, w = t >> 6;
    const int q = blockIdx.x*4 + w;
    const int b = q >> 10;
    const float* base = xyz + (size_t)b*NN*3;
    const float* qp = nxyz + (size_t)q*3;
    const float qx = qp[0], qy = qp[1], qz = qp[2];
    const float qsq = __fadd_rn(__fadd_rn(__fmul_rn(qx,qx),__fmul_rn(qy,qy)),__fmul_rn(qz,qz));

    unsigned int key[64];
    #pragma unroll
    for (int i = 0; i < 64; ++i){
        const int idx = (i<<6) + lane;
        const float* pp = base + 3*idx;
        float x = pp[0], y = pp[1], z = pp[2];
        float dot = __fadd_rn(__fadd_rn(__fmul_rn(qx,x),__fmul_rn(qy,y)),__fmul_rn(qz,z));
        float psq = __fadd_rn(__fadd_rn(__fmul_rn(x,x),__fmul_rn(y,y)),__fmul_rn(z,z));
        float d = __fadd_rn(__fadd_rn(__fmul_rn(-2.0f,dot),qsq),psq);
        key[i] = fkey(d);
    }
    unsigned int pref = 0; int need = 32;
    for (int bit = 31; bit >= 0; --bit){
        const unsigned int bound = 1u << bit;
        int c = 0;
        #pragma unroll
        for (int i = 0; i < 64; ++i) c += ((key[i] ^ pref) < bound) ? 1 : 0;
        int tot = __builtin_amdgcn_readlane(wave_incl_add(c), 63);
        if (tot < need){ need -= tot; pref |= bound; }
    }
    const unsigned int T = pref;
    int cl = 0;
    #pragma unroll
    for (int i = 0; i < 64; ++i) cl += (key[i] < T) ? 1 : 0;
    int incl_cl = wave_incl_add(cl);
    int clx = incl_cl - cl;
    int tiebase = __builtin_amdgcn_readlane(incl_cl, 63);
    int* oq = kidx + (size_t)q*NK;
    int pos = clx;
    #pragma unroll
    for (int i = 0; i < 64; ++i){
        if (key[i] < T){ oq[pos] = (i<<6) + lane; ++pos; }
    }
    int tcount = 0;
    for (int i = 0; i < 64 && tcount < need; ++i){
        u64 m = __ballot(key[i] == T);
        int myrank = (int)__popcll(m & ((1ull << lane) - 1ull));
        if ((key[i] == T) && (tcount + myrank < need))
            oq[tiebase + tcount + myrank] = (i<<6) + lane;
        tcount += (int)__popcll(m);
    }
}

// ---------------------------------------------------------------------------
// Fast BN finalize (r0/r3-validated, measured-cheap): 1 block x 1024 thr;
// 8-way row split + LDS tree. KEEP AS SEPARATE LAUNCHES (r4 lesson).
// ---------------------------------------------------------------------------
__global__ __launch_bounds__(1024) void finalize_kernel(const float* __restrict__ pin,
    const float* __restrict__ g, const float* __restrict__ beta, float* __restrict__ aff)
{
    __shared__ float l1[1024];
    const int t = threadIdx.x;
    const int stat = t & 127, seg = t >> 7;
    float S = 0.0f;
    #pragma unroll 8
    for (int r = seg*128; r < seg*128 + 128; ++r) S += pin[r*128 + stat];
    l1[t] = S;
    __syncthreads();
    if (t < 128){
        float s = l1[t] + l1[128+t] + l1[256+t] + l1[384+t]
                + l1[512+t] + l1[640+t] + l1[768+t] + l1[896+t];
        l1[t] = s;
    }
    __syncthreads();
    if (t < 64){
        float mean = l1[t] * (1.0f/(float)NP);
        float var  = fmaxf(l1[64+t] * (1.0f/(float)NP) - mean*mean, 0.0f);
        float sc = g[t] * rsqrtf(var + EPSBN);
        aff[t]    = sc;
        aff[64+t] = beta[t] - mean*sc;
    }
}

// ---------------------------------------------------------------------------
// MFMA conv core (r3 inner loop, byte-identical for ACT=0/1). ACT=2
// (r4/r5-validated): fused residual -- input = lrelu(affV(in) +
// lrelu(affY(in2))); packed x2 stored to x2out (for final_kernel) AND used
// as the MFMA operand. In-place out==in2 is safe: each row is owned by one
// wave; reads complete before its writes. Stats: non-atomic partials.
// ---------------------------------------------------------------------------
template<int ACT>
__global__ __launch_bounds__(256, (ACT==2)?2:3) void conv_mfma_kernel(
    const u16* __restrict__ in, const u16* __restrict__ in2,
    u16* __restrict__ out, u16* __restrict__ x2out,
    const u16* __restrict__ wfrag, const float* __restrict__ bias,
    const float* __restrict__ aff, const float* __restrict__ aff2,
    float* __restrict__ pout)
{
    __shared__ float sStat[4*128];
    const int t = threadIdx.x, lane = t & 63, wv = t >> 6;
    const int n = lane & 15, q = lane >> 4;
    const int bb = blockIdx.x;

    float scr[16], shr[16];
    float scr2[16], shr2[16];
    if (ACT){
        #pragma unroll
        for (int h = 0; h < 2; ++h){
            float4 a0 = *(const float4*)(aff + h*32 + q*8);
            float4 a1 = *(const float4*)(aff + h*32 + q*8 + 4);
            float4 b0 = *(const float4*)(aff + 64 + h*32 + q*8);
            float4 b1 = *(const float4*)(aff + 64 + h*32 + q*8 + 4);
            scr[h*8+0]=a0.x; scr[h*8+1]=a0.y; scr[h*8+2]=a0.z; scr[h*8+3]=a0.w;
            scr[h*8+4]=a1.x; scr[h*8+5]=a1.y; scr[h*8+6]=a1.z; scr[h*8+7]=a1.w;
            shr[h*8+0]=b0.x; shr[h*8+1]=b0.y; shr[h*8+2]=b0.z; shr[h*8+3]=b0.w;
            shr[h*8+4]=b1.x; shr[h*8+5]=b1.y; shr[h*8+6]=b1.z; shr[h*8+7]=b1.w;
        }
        if (ACT == 2){
            #pragma unroll
            for (int h = 0; h < 2; ++h){
                float4 a0 = *(const float4*)(aff2 + h*32 + q*8);
                float4 a1 = *(const float4*)(aff2 + h*32 + q*8 + 4);
                float4 b0 = *(const float4*)(aff2 + 64 + h*32 + q*8);
                float4 b1 = *(const float4*)(aff2 + 64 + h*32 + q*8 + 4);
                scr2[h*8+0]=a0.x; scr2[h*8+1]=a0.y; scr2[h*8+2]=a0.z; scr2[h*8+3]=a0.w;
                scr2[h*8+4]=a1.x; scr2[h*8+5]=a1.y; scr2[h*8+6]=a1.z; scr2[h*8+7]=a1.w;
                shr2[h*8+0]=b0.x; shr2[h*8+1]=b0.y; shr2[h*8+2]=b0.z; shr2[h*8+3]=b0.w;
                shr2[h*8+4]=b1.x; shr2[h*8+5]=b1.y; shr2[h*8+6]=b1.z; shr2[h*8+7]=b1.w;
            }
        }
    }
    bf8_t wf[8];
    #pragma unroll
    for (int f = 0; f < 8; ++f)
        wf[f] = *(const bf8_t*)(wfrag + (f*64 + lane)*8);
    f4_t bv[4];
    #pragma unroll
    for (int mt = 0; mt < 4; ++mt)
        bv[mt] = *(const f4_t*)(bias + mt*16 + q*4);

    float st1[16], st2[16];
    #pragma unroll
    for (int e = 0; e < 16; ++e){ st1[e] = 0.0f; st2[e] = 0.0f; }

    #pragma unroll
    for (int i = 0; i < 4; ++i){
        const int p0 = bb*256 + wv*64 + i*16;
        const u16* row = in + (size_t)(p0 + n)*64;
        bf8_t bf0, bf1;
        union { unsigned u[4]; bf8_t v; } B0, B1;
        if (ACT == 1){
            uint4 r0 = *(const uint4*)(row + q*8);
            uint4 r1 = *(const uint4*)(row + 32 + q*8);
            const unsigned ra[4] = {r0.x, r0.y, r0.z, r0.w};
            const unsigned rb[4] = {r1.x, r1.y, r1.z, r1.w};
            #pragma unroll
            for (int d = 0; d < 4; ++d){
                float x0 = bflo(ra[d]), x1 = bfhi(ra[d]);
                float y0 = fmaf(scr[2*d],   x0, shr[2*d]);   y0 = lrelu(y0);
                float y1 = fmaf(scr[2*d+1], x1, shr[2*d+1]); y1 = lrelu(y1);
                B0.u[d] = f2bf(y0) | (f2bf(y1) << 16);
                float z0 = bflo(rb[d]), z1 = bfhi(rb[d]);
                float w0 = fmaf(scr[8+2*d],   z0, shr[8+2*d]);   w0 = lrelu(w0);
                float w1 = fmaf(scr[8+2*d+1], z1, shr[8+2*d+1]); w1 = lrelu(w1);
                B1.u[d] = f2bf(w0) | (f2bf(w1) << 16);
            }
            bf0 = B0.v; bf1 = B1.v;
        } else if (ACT == 2){ // fused residual (exact resid_kernel arithmetic)
            const u16* yrow = in2 + (size_t)(p0 + n)*64;
            uint4 r0 = *(const uint4*)(row + q*8);
            uint4 r1 = *(const uint4*)(row + 32 + q*8);
            uint4 s0 = *(const uint4*)(yrow + q*8);
            uint4 s1 = *(const uint4*)(yrow + 32 + q*8);
            const unsigned ra[4] = {r0.x, r0.y, r0.z, r0.w};
            const unsigned rb[4] = {r1.x, r1.y, r1.z, r1.w};
            const unsigned ya[4] = {s0.x, s0.y, s0.z, s0.w};
            const unsigned yb[4] = {s1.x, s1.y, s1.z, s1.w};
            #pragma unroll
            for (int d = 0; d < 4; ++d){
                float t0 = lrelu(fmaf(scr2[2*d],   bflo(ya[d]), shr2[2*d]));
                float t1 = lrelu(fmaf(scr2[2*d+1], bfhi(ya[d]), shr2[2*d+1]));
                float x0 = lrelu(fmaf(scr[2*d],    bflo(ra[d]), shr[2*d])   + t0);
                float x1 = lrelu(fmaf(scr[2*d+1],  bfhi(ra[d]), shr[2*d+1]) + t1);
                B0.u[d] = f2bf(x0) | (f2bf(x1) << 16);
                float u0 = lrelu(fmaf(scr2[8+2*d],   bflo(yb[d]), shr2[8+2*d]));
                float u1 = lrelu(fmaf(scr2[8+2*d+1], bfhi(yb[d]), shr2[8+2*d+1]));
                float v0 = lrelu(fmaf(scr[8+2*d],    bflo(rb[d]), shr[8+2*d])   + u0);
                float v1 = lrelu(fmaf(scr[8+2*d+1],  bfhi(rb[d]), shr[8+2*d+1]) + u1);
                B1.u[d] = f2bf(v0) | (f2bf(v1) << 16);
            }
            u16* xrow = x2out + (size_t)(p0 + n)*64;
            *(uint4*)(xrow + q*8)      = (uint4){B0.u[0],B0.u[1],B0.u[2],B0.u[3]};
            *(uint4*)(xrow + 32 + q*8) = (uint4){B1.u[0],B1.u[1],B1.u[2],B1.u[3]};
            bf0 = B0.v; bf1 = B1.v;
        } else {
            bf0 = *(const bf8_t*)(row + q*8);
            bf1 = *(const bf8_t*)(row + 32 + q*8);
        }
        f4_t acc[4];
        #pragma unroll
        for (int mt = 0; mt < 4; ++mt){
            acc[mt] = (f4_t){0.f,0.f,0.f,0.f};
            acc[mt] = __builtin_amdgcn_mfma_f32_16x16x32_bf16(wf[mt*2+0], bf0, acc[mt], 0,0,0);
            acc[mt] = __builtin_amdgcn_mfma_f32_16x16x32_bf16(wf[mt*2+1], bf1, acc[mt], 0,0,0);
        }
        u16* orow = out + (size_t)(p0 + n)*64;
        #pragma unroll
        for (int mt = 0; mt < 4; ++mt){
            float v0 = acc[mt].x + bv[mt].x;
            float v1 = acc[mt].y + bv[mt].y;
            float v2 = acc[mt].z + bv[mt].z;
            float v3 = acc[mt].w + bv[mt].w;
            st1[mt*4+0] += v0; st2[mt*4+0] += v0*v0;
            st1[mt*4+1] += v1; st2[mt*4+1] += v1*v1;
            st1[mt*4+2] += v2; st2[mt*4+2] += v2*v2;
            st1[mt*4+3] += v3; st2[mt*4+3] += v3*v3;
            uint2 pk;
            pk.x = f2bf(v0) | (f2bf(v1) << 16);
            pk.y = f2bf(v2) | (f2bf(v3) << 16);
            *(uint2*)(orow + mt*16 + q*4) = pk;
        }
    }
    #pragma unroll
    for (int e = 0; e < 16; ++e){
        float r1 = row_sum16(st1[e]);
        float r2 = row_sum16(st2[e]);
        if (n == 15){
            const int ch = (e >> 2)*16 + q*4 + (e & 3);
            sStat[wv*128 + ch]      = r1;
            sStat[wv*128 + 64 + ch] = r2;
        }
    }
    __syncthreads();
    if (t < 128){
        float s = sStat[t] + sStat[128+t] + sStat[256+t] + sStat[384+t];
        pout[(size_t)bb*128 + t] = s;
    }
}

// ---------------------------------------------------------------------------
// Fused gather + conv_t (MFMA), bf16 gather (r3-validated).
// ---------------------------------------------------------------------------
__global__ __launch_bounds__(256,3) void gconv_mfma_kernel(const u16* __restrict__ fbf,
    const int* __restrict__ kidx, u16* __restrict__ out,
    const u16* __restrict__ wfrag, const float* __restrict__ bias,
    float* __restrict__ pout)
{
    __shared__ float sStat[4*128];
    const int t = threadIdx.x, lane = t & 63, wv = t >> 6;
    const int n = lane & 15, q = lane >> 4;
    const int bb = blockIdx.x;

    bf8_t wf[8];
    #pragma unroll
    for (int f = 0; f < 8; ++f)
        wf[f] = *(const bf8_t*)(wfrag + (f*64 + lane)*8);
    f4_t bv[4];
    #pragma unroll
    for (int mt = 0; mt < 4; ++mt)
        bv[mt] = *(const f4_t*)(bias + mt*16 + q*4);

    float st1[16], st2[16];
    #pragma unroll
    for (int e = 0; e < 16; ++e){ st1[e] = 0.0f; st2[e] = 0.0f; }

    #pragma unroll
    for (int i = 0; i < 4; ++i){
        const int p0 = bb*256 + wv*64 + i*16;
        const int p = p0 + n;
        const int b = p >> 15;
        const int idx = kidx[p];
        const u16* frow = fbf + ((size_t)b*NN + idx)*NC;
        bf8_t bf0 = *(const bf8_t*)(frow + q*8);
        bf8_t bf1 = *(const bf8_t*)(frow + 32 + q*8);
        f4_t acc[4];
        #pragma unroll
        for (int mt = 0; mt < 4; ++mt){
            acc[mt] = (f4_t){0.f,0.f,0.f,0.f};
            acc[mt] = __builtin_amdgcn_mfma_f32_16x16x32_bf16(wf[mt*2+0], bf0, acc[mt], 0,0,0);
            acc[mt] = __builtin_amdgcn_mfma_f32_16x16x32_bf16(wf[mt*2+1], bf1, acc[mt], 0,0,0);
        }
        u16* orow = out + (size_t)p*64;
        #pragma unroll
        for (int mt = 0; mt < 4; ++mt){
            float v0 = acc[mt].x + bv[mt].x;
            float v1 = acc[mt].y + bv[mt].y;
            float v2 = acc[mt].z + bv[mt].z;
            float v3 = acc[mt].w + bv[mt].w;
            st1[mt*4+0] += v0; st2[mt*4+0] += v0*v0;
            st1[mt*4+1] += v1; st2[mt*4+1] += v1*v1;
            st1[mt*4+2] += v2; st2[mt*4+2] += v2*v2;
            st1[mt*4+3] += v3; st2[mt*4+3] += v3*v3;
            uint2 pk;
            pk.x = f2bf(v0) | (f2bf(v1) << 16);
            pk.y = f2bf(v2) | (f2bf(v3) << 16);
            *(uint2*)(orow + mt*16 + q*4) = pk;
        }
    }
    #pragma unroll
    for (int e = 0; e < 16; ++e){
        float r1 = row_sum16(st1[e]);
        float r2 = row_sum16(st2[e]);
        if (n == 15){
            const int ch = (e >> 2)*16 + q*4 + (e & 3);
            sStat[wv*128 + ch]      = r1;
            sStat[wv*128 + 64 + ch] = r2;
        }
    }
    __syncthreads();
    if (t < 128){
        float s = sStat[t] + sStat[128+t] + sStat[256+t] + sStat[384+t];
        pout[(size_t)bb*128 + t] = s;
    }
}

// ---------------------------------------------------------------------------
// Final: x3 = leaky(aff(v2) + x2); out1[b,c,s] = max over 32 K-rows. (r0)
// ---------------------------------------------------------------------------
__global__ __launch_bounds__(256,2) void final_kernel(const u16* __restrict__ v2,
    const u16* __restrict__ x2, const float* __restrict__ aff,
    float* __restrict__ out1)
{
    const int t = threadIdx.x;
    const int dc = t & 31, sg = t >> 5;
    const int c0 = dc*2, c1 = c0 + 1;
    const float a0 = aff[c0], s0 = aff[64+c0];
    const float a1 = aff[c1], s1 = aff[64+c1];
    const int s = blockIdx.x*8 + sg;
    const unsigned* vp = (const unsigned*)v2;
    const unsigned* xp = (const unsigned*)x2;
    float m0 = -3.0e38f, m1 = -3.0e38f;
    #pragma unroll 8
    for (int kk = 0; kk < 32; ++kk){
        const size_t e = ((size_t)s*32 + kk)*32 + dc;
        unsigned uv = vp[e], ux = xp[e];
        m0 = fmaxf(m0, lrelu(fmaf(a0, bflo(uv), s0) + bflo(ux)));
        m1 = fmaxf(m1, lrelu(fmaf(a1, bfhi(uv), s1) + bfhi(ux)));
    }
    const int b = s >> 10, sl = s & 1023;
    out1[((size_t)b*NC + c0)*NS + sl] = m0;
    out1[((size_t)b*NC + c1)*NS + sl] = m1;
}

// ---------------------------------------------------------------------------
extern "C" void kernel_launch(void* const* d_in, const int* in_sizes, int n_in,
                              void* d_out, int out_size, void* d_ws, size_t ws_size,
                              hipStream_t stream)
{
    const float* xyz      = (const float*)d_in[0];
    const float* features = (const float*)d_in[1];
    const float* w_t    = (const float*)d_in[2];
    const float* w1_0   = (const float*)d_in[3];
    const float* w2_0   = (const float*)d_in[4];
    const float* w1_1   = (const float*)d_in[5];
    const float* w2_1   = (const float*)d_in[6];
    const float* b_t    = (const float*)d_in[7];
    const float* b1_0   = (const float*)d_in[8];
    const float* b2_0   = (const float*)d_in[9];
    const float* b1_1   = (const float*)d_in[10];
    const float* b2_1   = (const float*)d_in[11];
    const float* g_t    = (const float*)d_in[12];
    const float* g1_0   = (const float*)d_in[13];
    const float* g2_0   = (const float*)d_in[14];
    const float* g1_1   = (const float*)d_in[15];
    const float* g2_1   = (const float*)d_in[16];
    const float* beta_t  = (const float*)d_in[17];
    const float* beta1_0 = (const float*)d_in[18];
    const float* beta2_0 = (const float*)d_in[19];
    const float* beta1_1 = (const float*)d_in[20];
    const float* beta2_1 = (const float*)d_in[21];

    float* out = (float*)d_out;

    float* nxyz = (float*)d_ws;                          // 24576 f
    int*   kidx = (int*)(nxyz + 24576);                  // NP ints
    float* pT   = (float*)(kidx + NP);                   // 5 x 1024*128 partials
    float* p10  = pT  + 131072;
    float* p20  = p10 + 131072;
    float* p11  = p20 + 131072;
    float* p21  = p11 + 131072;
    float* affT  = p21 + 131072;                         // 5 x 128
    float* aff10 = affT + 128;
    float* aff20 = aff10 + 128;
    float* aff11 = aff20 + 128;
    float* aff21 = aff11 + 128;
    u16*  bwt  = (u16*)(aff21 + 128);                    // 5*4096 u16
    u16*  buf0 = bwt + 5*4096;                           // 3 x NP*64 bf16
    u16*  buf1 = buf0 + (size_t)NP*NC;
    u16*  buf2 = buf1 + (size_t)NP*NC;
    u16*  fbf  = buf2;   // bf16 features alias buf2 (dead before conv#2 writes it)

    // blocks 0..3: FPS (2 batches each); 4..515: feature f32->bf16; 516..520: wtrans
    fps_kernel<<<4 + 512 + 5, 256, 0, stream>>>(xyz, out, nxyz, features, fbf,
                                                w_t, w1_0, w2_0, w1_1, w2_1, bwt);
    knn_kernel<<<NQ/4, 256, 0, stream>>>(xyz, nxyz, kidx);

    // conv_t (gather fused, bf16 gather) -> buf1, stats pT
    gconv_mfma_kernel<<<1024, 256, 0, stream>>>(fbf, kidx, buf1,
                                                bwt + 0*4096, b_t, pT);
    finalize_kernel<<<1, 1024, 0, stream>>>(pT, g_t, beta_t, affT);
    // resblock 0
    conv_mfma_kernel<1><<<1024, 256, 0, stream>>>(buf1, nullptr, buf0, nullptr,
                                                  bwt + 1*4096, b1_0, affT, nullptr, p10);
    finalize_kernel<<<1, 1024, 0, stream>>>(p10, g1_0, beta1_0, aff10);
    conv_mfma_kernel<1><<<1024, 256, 0, stream>>>(buf0, nullptr, buf2, nullptr,
                                                  bwt + 2*4096, b2_0, aff10, nullptr, p20);
    finalize_kernel<<<1, 1024, 0, stream>>>(p20, g2_0, beta2_0, aff20);
    // resblock 1 first conv with residual fused:
    //   v=buf2 (aff20), y=buf1 (affT) -> x2=buf0 (for final), out=buf1
    conv_mfma_kernel<2><<<1024, 256, 0, stream>>>(buf2, buf1, buf1, buf0,
                                                  bwt + 3*4096, b1_1, aff20, affT, p11);
    finalize_kernel<<<1, 1024, 0, stream>>>(p11, g1_1, beta1_1, aff11);
    conv_mfma_kernel<1><<<1024, 256, 0, stream>>>(buf1, nullptr, buf2, nullptr,
                                                  bwt + 4*4096, b2_1, aff11, nullptr, p21);
    finalize_kernel<<<1, 1024, 0, stream>>>(p21, g2_1, beta2_1, aff21);
    // epilogue: residual + max over K
    final_kernel<<<1024, 256, 0, stream>>>(buf2, buf0, aff21,
                                           out + (size_t)NB*3*NS);
}

// Round 7
// 908.609 us; speedup vs baseline: 1.4680x; 1.4680x over previous
//
#include <hip/hip_runtime.h>
#include <stdint.h>

#define NB 8
#define NN 4096
#define NC 64
#define NS 1024
#define NK 32
#define NQ (NB*NS)        /* 8192 queries */
#define NP (NQ*NK)        /* 262144 positions */
#define EPSBN 1e-5f

typedef unsigned long long u64;
typedef unsigned short u16;
typedef float v2f __attribute__((ext_vector_type(2)));
typedef short bf8_t __attribute__((ext_vector_type(8)));    // 8 bf16 (4 VGPRs)
typedef float f4_t __attribute__((ext_vector_type(4)));     // MFMA acc

__device__ __forceinline__ float lrelu(float x){ return x >= 0.0f ? x : 0.1f*x; }

__device__ __forceinline__ unsigned int fkey(float d){
    unsigned int fb = __float_as_uint(d);
    return (fb & 0x80000000u) ? ~fb : (fb | 0x80000000u);
}
// f32 -> bf16 RNE
__device__ __forceinline__ unsigned f2bf(float f){
    unsigned u = __float_as_uint(f);
    return (u + 0x7fffu + ((u >> 16) & 1u)) >> 16;
}
__device__ __forceinline__ float bflo(unsigned u){ return __uint_as_float(u << 16); }
__device__ __forceinline__ float bfhi(unsigned u){ return __uint_as_float(u & 0xffff0000u); }

// inclusive prefix-sum over 64 lanes (ints)
__device__ __forceinline__ int wave_incl_add(int x){
    int v = x;
    {int o=__builtin_amdgcn_update_dpp(0,v,0x111,0xf,0xf,true); v+=o;}
    {int o=__builtin_amdgcn_update_dpp(0,v,0x112,0xf,0xf,true); v+=o;}
    {int o=__builtin_amdgcn_update_dpp(0,v,0x114,0xf,0xf,true); v+=o;}
    {int o=__builtin_amdgcn_update_dpp(0,v,0x118,0xf,0xf,true); v+=o;}
    {int o=__builtin_amdgcn_update_dpp(0,v,0x142,0xa,0xf,true); v+=o;}
    {int o=__builtin_amdgcn_update_dpp(0,v,0x143,0xc,0xf,true); v+=o;}
    return v;
}
// sum within each 16-lane row; valid at lane%16==15
__device__ __forceinline__ float row_sum16(float x){
    int v = __float_as_int(x);
    {int o=__builtin_amdgcn_update_dpp(0,v,0x111,0xf,0xf,true); v=__float_as_int(__int_as_float(v)+__int_as_float(o));}
    {int o=__builtin_amdgcn_update_dpp(0,v,0x112,0xf,0xf,true); v=__float_as_int(__int_as_float(v)+__int_as_float(o));}
    {int o=__builtin_amdgcn_update_dpp(0,v,0x114,0xf,0xf,true); v=__float_as_int(__int_as_float(v)+__int_as_float(o));}
    {int o=__builtin_amdgcn_update_dpp(0,v,0x118,0xf,0xf,true); v=__float_as_int(__int_as_float(v)+__int_as_float(o));}
    return __int_as_float(v);
}
// max-reduce of a packed positive double across the wave, via DPP pairs
__device__ __forceinline__ double wave_max_d(double x){
    int lo = __double2loint(x), hi = __double2hiint(x);
    #define FPS_STG(ctl) { \
        int nl=__builtin_amdgcn_update_dpp(lo,lo,ctl,0xf,0xf,false); \
        int nh=__builtin_amdgcn_update_dpp(hi,hi,ctl,0xf,0xf,false); \
        double mx=fmax(__hiloint2double(hi,lo), __hiloint2double(nh,nl)); \
        lo=__double2loint(mx); hi=__double2hiint(mx); }
    FPS_STG(0x111) FPS_STG(0x112) FPS_STG(0x114) FPS_STG(0x118) FPS_STG(0x142) FPS_STG(0x143)
    #undef FPS_STG
    int flo = __builtin_amdgcn_readlane(lo, 63);
    int fhi = __builtin_amdgcn_readlane(hi, 63);
    return __hiloint2double(fhi, flo);
}

// ---------------------------------------------------------------------------
// FPS: r5 structure (1 batch/block, 8 blocks, 256 thr, 16 pts/thread, v2f
// update, packed f64 argmax key {dist_bits, ~idx}, DPP wave reduce, 4 LDS
// slots, parity double-buffer) + r7 change: 4-accumulator fmax TREE in the
// key accumulation (chain depth 16 -> 6; fmax associative, keys unique ->
// bit-identical selection). This isolates the tree from r1's confounded
// bundle (float4 LDS caused that regression: conflicts 6.6K->30K).
// A/B LESSONS (do not redo): float4 LDS coords; 512thr x 8pts (571us);
// r4 per-block __threadfence (+650us); r6 2-batches/block (938us -- FPS is
// VALU-throughput-bound per CU: 291us issue/batch; keep 1 batch/CU).
// Piggybacks on the idle CUs (validated free):
//   blocks NB..NB+511:    features f32->bf16
//   blocks NB+512..+516:  weight A-frag pack
// ---------------------------------------------------------------------------
__global__ __launch_bounds__(256,1) void fps_kernel(const float* __restrict__ xyz,
    float* __restrict__ out0, float* __restrict__ nxyz,
    const float* __restrict__ features, u16* __restrict__ fbf,
    const float* __restrict__ w0, const float* __restrict__ w1,
    const float* __restrict__ w2, const float* __restrict__ w3,
    const float* __restrict__ w4, u16* __restrict__ bwt)
{
    if (blockIdx.x >= NB + 512){
        // weight pack (5 blocks)
        const int wb = blockIdx.x - (NB + 512);
        const float* s;
        switch (wb){
            case 0: s = w0; break; case 1: s = w1; break; case 2: s = w2; break;
            case 3: s = w3; break; default: s = w4; break;
        }
        u16* d = bwt + (size_t)wb*4096;
        for (int i = threadIdx.x; i < 4096; i += 256){
            const int f = i >> 9, lane = (i >> 3) & 63, j = i & 7;
            const int mt = f >> 1, h = f & 1;
            const int o = mt*16 + (lane & 15);
            const int c = h*32 + (lane >> 4)*8 + j;
            d[i] = (u16)f2bf(s[o*64 + c]);
        }
        return;
    }
    if (blockIdx.x >= NB){
        // feature pre-conversion: 2M floats -> bf16
        const int cb = blockIdx.x - NB;
        const float4* src = (const float4*)features;
        uint2* dst = (uint2*)fbf;
        for (int i = cb*256 + threadIdx.x; i < NB*NN*NC/4; i += 512*256){
            float4 v = src[i];
            uint2 pk;
            pk.x = f2bf(v.x) | (f2bf(v.y) << 16);
            pk.y = f2bf(v.z) | (f2bf(v.w) << 16);
            dst[i] = pk;
        }
        return;
    }
    __shared__ float sX[NN], sY[NN], sZ[NN];
    __shared__ double slots[2][4];
    __shared__ int sFar[NS];
    const int b = blockIdx.x, t = threadIdx.x;
    const int lane = t & 63, wv = t >> 6;
    const float* base = xyz + (size_t)b*NN*3;
    for (int i = t; i < NN; i += 256){
        const float* pp = base + 3*i;
        sX[i] = pp[0]; sY[i] = pp[1]; sZ[i] = pp[2];
    }
    __syncthreads();
    v2f PX[8], PY[8], PZ[8], D[8];
    int LO[16];
    const int pb = t*16;
    #pragma unroll
    for (int j = 0; j < 8; ++j){
        PX[j] = (v2f){ sX[pb+2*j], sX[pb+2*j+1] };
        PY[j] = (v2f){ sY[pb+2*j], sY[pb+2*j+1] };
        PZ[j] = (v2f){ sZ[pb+2*j], sZ[pb+2*j+1] };
        D[j]  = (v2f){ 1e10f, 1e10f };
    }
    #pragma unroll
    for (int j = 0; j < 16; ++j) LO[j] = (int)(~(unsigned)(pb + j));
    int far = 0;
    float cx = sX[0], cy = sY[0], cz = sZ[0];
    for (int s = 0; s < NS; ++s){
        if (t == 255) sFar[s] = far;
        double best;
        {
            #pragma clang fp contract(off)
            v2f cx2 = (v2f){cx, cx}, cy2 = (v2f){cy, cy}, cz2 = (v2f){cz, cz};
            double b0 = -1.0, b1 = -1.0, b2 = -1.0, b3 = -1.0;
            #pragma unroll
            for (int j = 0; j < 8; ++j){
                v2f dx = PX[j] - cx2;
                v2f dy = PY[j] - cy2;
                v2f dz = PZ[j] - cz2;
                v2f dd = (dx*dx + dy*dy) + dz*dz;
                v2f nd = __builtin_elementwise_min(D[j], dd);
                D[j] = nd;
                double k0 = __hiloint2double(__float_as_int(nd.x), LO[2*j]);
                double k1 = __hiloint2double(__float_as_int(nd.y), LO[2*j+1]);
                if (j & 1){ b1 = fmax(b1, k0); b3 = fmax(b3, k1); }
                else      { b0 = fmax(b0, k0); b2 = fmax(b2, k1); }
            }
            best = fmax(fmax(b0, b1), fmax(b2, b3));
        }
        double wb = wave_max_d(best);
        const int par = s & 1;
        if (lane == 0) slots[par][wv] = wb;
        __syncthreads();
        double s0 = slots[par][0], s1 = slots[par][1];
        double s2 = slots[par][2], s3 = slots[par][3];
        double mm = fmax(fmax(s0, s1), fmax(s2, s3));
        far = (int)(~(unsigned)__double2loint(mm));
        cx = sX[far]; cy = sY[far]; cz = sZ[far];
    }
    __syncthreads();
    for (int s = t; s < NS; s += 256){
        const int f = sFar[s];
        const float x = sX[f], y = sY[f], z = sZ[f];
        float* npq = nxyz + ((size_t)b*NS + s)*3;
        npq[0]=x; npq[1]=y; npq[2]=z;
        out0[(b*3+0)*NS+s]=x; out0[(b*3+1)*NS+s]=y; out0[(b*3+2)*NS+s]=z;
    }
}

// ---------------------------------------------------------------------------
// KNN (unchanged): exact 32nd-smallest via bitwise binary search on fkey.
// ---------------------------------------------------------------------------
__global__ __launch_bounds__(256,2) void knn_kernel(const float* __restrict__ xyz,
                                                    const float* __restrict__ nxyz,
                                                    int* __restrict__ kidx)
{
    const int t = threadIdx.x, lane = t & 63, w = t >> 6;
    const int q = blockIdx.x*4 + w;
    const int b = q >> 10;
    const float* base = xyz + (size_t)b*NN*3;
    const float* qp = nxyz + (size_t)q*3;
    const float qx = qp[0], qy = qp[1], qz = qp[2];
    const float qsq = __fadd_rn(__fadd_rn(__fmul_rn(qx,qx),__fmul_rn(qy,qy)),__fmul_rn(qz,qz));

    unsigned int key[64];
    #pragma unroll
    for (int i = 0; i < 64; ++i){
        const int idx = (i<<6) + lane;
        const float* pp = base + 3*idx;
        float x = pp[0], y = pp[1], z = pp[2];
        float dot = __fadd_rn(__fadd_rn(__fmul_rn(qx,x),__fmul_rn(qy,y)),__fmul_rn(qz,z));
        float psq = __fadd_rn(__fadd_rn(__fmul_rn(x,x),__fmul_rn(y,y)),__fmul_rn(z,z));
        float d = __fadd_rn(__fadd_rn(__fmul_rn(-2.0f,dot),qsq),psq);
        key[i] = fkey(d);
    }
    unsigned int pref = 0; int need = 32;
    for (int bit = 31; bit >= 0; --bit){
        const unsigned int bound = 1u << bit;
        int c = 0;
        #pragma unroll
        for (int i = 0; i < 64; ++i) c += ((key[i] ^ pref) < bound) ? 1 : 0;
        int tot = __builtin_amdgcn_readlane(wave_incl_add(c), 63);
        if (tot < need){ need -= tot; pref |= bound; }
    }
    const unsigned int T = pref;
    int cl = 0;
    #pragma unroll
    for (int i = 0; i < 64; ++i) cl += (key[i] < T) ? 1 : 0;
    int incl_cl = wave_incl_add(cl);
    int clx = incl_cl - cl;
    int tiebase = __builtin_amdgcn_readlane(incl_cl, 63);
    int* oq = kidx + (size_t)q*NK;
    int pos = clx;
    #pragma unroll
    for (int i = 0; i < 64; ++i){
        if (key[i] < T){ oq[pos] = (i<<6) + lane; ++pos; }
    }
    int tcount = 0;
    for (int i = 0; i < 64 && tcount < need; ++i){
        u64 m = __ballot(key[i] == T);
        int myrank = (int)__popcll(m & ((1ull << lane) - 1ull));
        if ((key[i] == T) && (tcount + myrank < need))
            oq[tiebase + tcount + myrank] = (i<<6) + lane;
        tcount += (int)__popcll(m);
    }
}

// ---------------------------------------------------------------------------
// Fast BN finalize (r0/r3-validated, measured-cheap): 1 block x 1024 thr;
// 8-way row split + LDS tree. KEEP AS SEPARATE LAUNCHES (r4 lesson).
// ---------------------------------------------------------------------------
__global__ __launch_bounds__(1024) void finalize_kernel(const float* __restrict__ pin,
    const float* __restrict__ g, const float* __restrict__ beta, float* __restrict__ aff)
{
    __shared__ float l1[1024];
    const int t = threadIdx.x;
    const int stat = t & 127, seg = t >> 7;
    float S = 0.0f;
    #pragma unroll 8
    for (int r = seg*128; r < seg*128 + 128; ++r) S += pin[r*128 + stat];
    l1[t] = S;
    __syncthreads();
    if (t < 128){
        float s = l1[t] + l1[128+t] + l1[256+t] + l1[384+t]
                + l1[512+t] + l1[640+t] + l1[768+t] + l1[896+t];
        l1[t] = s;
    }
    __syncthreads();
    if (t < 64){
        float mean = l1[t] * (1.0f/(float)NP);
        float var  = fmaxf(l1[64+t] * (1.0f/(float)NP) - mean*mean, 0.0f);
        float sc = g[t] * rsqrtf(var + EPSBN);
        aff[t]    = sc;
        aff[64+t] = beta[t] - mean*sc;
    }
}

// ---------------------------------------------------------------------------
// MFMA conv core (r3 inner loop, byte-identical for ACT=0/1). ACT=2
// (r4/r5-validated): fused residual -- input = lrelu(affV(in) +
// lrelu(affY(in2))); packed x2 stored to x2out (for final_kernel) AND used
// as the MFMA operand. In-place out==in2 is safe: each row is owned by one
// wave; reads complete before its writes. Stats: non-atomic partials.
// ---------------------------------------------------------------------------
template<int ACT>
__global__ __launch_bounds__(256, (ACT==2)?2:3) void conv_mfma_kernel(
    const u16* __restrict__ in, const u16* __restrict__ in2,
    u16* __restrict__ out, u16* __restrict__ x2out,
    const u16* __restrict__ wfrag, const float* __restrict__ bias,
    const float* __restrict__ aff, const float* __restrict__ aff2,
    float* __restrict__ pout)
{
    __shared__ float sStat[4*128];
    const int t = threadIdx.x, lane = t & 63, wv = t >> 6;
    const int n = lane & 15, q = lane >> 4;
    const int bb = blockIdx.x;

    float scr[16], shr[16];
    float scr2[16], shr2[16];
    if (ACT){
        #pragma unroll
        for (int h = 0; h < 2; ++h){
            float4 a0 = *(const float4*)(aff + h*32 + q*8);
            float4 a1 = *(const float4*)(aff + h*32 + q*8 + 4);
            float4 b0 = *(const float4*)(aff + 64 + h*32 + q*8);
            float4 b1 = *(const float4*)(aff + 64 + h*32 + q*8 + 4);
            scr[h*8+0]=a0.x; scr[h*8+1]=a0.y; scr[h*8+2]=a0.z; scr[h*8+3]=a0.w;
            scr[h*8+4]=a1.x; scr[h*8+5]=a1.y; scr[h*8+6]=a1.z; scr[h*8+7]=a1.w;
            shr[h*8+0]=b0.x; shr[h*8+1]=b0.y; shr[h*8+2]=b0.z; shr[h*8+3]=b0.w;
            shr[h*8+4]=b1.x; shr[h*8+5]=b1.y; shr[h*8+6]=b1.z; shr[h*8+7]=b1.w;
        }
        if (ACT == 2){
            #pragma unroll
            for (int h = 0; h < 2; ++h){
                float4 a0 = *(const float4*)(aff2 + h*32 + q*8);
                float4 a1 = *(const float4*)(aff2 + h*32 + q*8 + 4);
                float4 b0 = *(const float4*)(aff2 + 64 + h*32 + q*8);
                float4 b1 = *(const float4*)(aff2 + 64 + h*32 + q*8 + 4);
                scr2[h*8+0]=a0.x; scr2[h*8+1]=a0.y; scr2[h*8+2]=a0.z; scr2[h*8+3]=a0.w;
                scr2[h*8+4]=a1.x; scr2[h*8+5]=a1.y; scr2[h*8+6]=a1.z; scr2[h*8+7]=a1.w;
                shr2[h*8+0]=b0.x; shr2[h*8+1]=b0.y; shr2[h*8+2]=b0.z; shr2[h*8+3]=b0.w;
                shr2[h*8+4]=b1.x; shr2[h*8+5]=b1.y; shr2[h*8+6]=b1.z; shr2[h*8+7]=b1.w;
            }
        }
    }
    bf8_t wf[8];
    #pragma unroll
    for (int f = 0; f < 8; ++f)
        wf[f] = *(const bf8_t*)(wfrag + (f*64 + lane)*8);
    f4_t bv[4];
    #pragma unroll
    for (int mt = 0; mt < 4; ++mt)
        bv[mt] = *(const f4_t*)(bias + mt*16 + q*4);

    float st1[16], st2[16];
    #pragma unroll
    for (int e = 0; e < 16; ++e){ st1[e] = 0.0f; st2[e] = 0.0f; }

    #pragma unroll
    for (int i = 0; i < 4; ++i){
        const int p0 = bb*256 + wv*64 + i*16;
        const u16* row = in + (size_t)(p0 + n)*64;
        bf8_t bf0, bf1;
        union { unsigned u[4]; bf8_t v; } B0, B1;
        if (ACT == 1){
            uint4 r0 = *(const uint4*)(row + q*8);
            uint4 r1 = *(const uint4*)(row + 32 + q*8);
            const unsigned ra[4] = {r0.x, r0.y, r0.z, r0.w};
            const unsigned rb[4] = {r1.x, r1.y, r1.z, r1.w};
            #pragma unroll
            for (int d = 0; d < 4; ++d){
                float x0 = bflo(ra[d]), x1 = bfhi(ra[d]);
                float y0 = fmaf(scr[2*d],   x0, shr[2*d]);   y0 = lrelu(y0);
                float y1 = fmaf(scr[2*d+1], x1, shr[2*d+1]); y1 = lrelu(y1);
                B0.u[d] = f2bf(y0) | (f2bf(y1) << 16);
                float z0 = bflo(rb[d]), z1 = bfhi(rb[d]);
                float w0 = fmaf(scr[8+2*d],   z0, shr[8+2*d]);   w0 = lrelu(w0);
                float w1 = fmaf(scr[8+2*d+1], z1, shr[8+2*d+1]); w1 = lrelu(w1);
                B1.u[d] = f2bf(w0) | (f2bf(w1) << 16);
            }
            bf0 = B0.v; bf1 = B1.v;
        } else if (ACT == 2){ // fused residual (exact resid_kernel arithmetic)
            const u16* yrow = in2 + (size_t)(p0 + n)*64;
            uint4 r0 = *(const uint4*)(row + q*8);
            uint4 r1 = *(const uint4*)(row + 32 + q*8);
            uint4 s0 = *(const uint4*)(yrow + q*8);
            uint4 s1 = *(const uint4*)(yrow + 32 + q*8);
            const unsigned ra[4] = {r0.x, r0.y, r0.z, r0.w};
            const unsigned rb[4] = {r1.x, r1.y, r1.z, r1.w};
            const unsigned ya[4] = {s0.x, s0.y, s0.z, s0.w};
            const unsigned yb[4] = {s1.x, s1.y, s1.z, s1.w};
            #pragma unroll
            for (int d = 0; d < 4; ++d){
                float t0 = lrelu(fmaf(scr2[2*d],   bflo(ya[d]), shr2[2*d]));
                float t1 = lrelu(fmaf(scr2[2*d+1], bfhi(ya[d]), shr2[2*d+1]));
                float x0 = lrelu(fmaf(scr[2*d],    bflo(ra[d]), shr[2*d])   + t0);
                float x1 = lrelu(fmaf(scr[2*d+1],  bfhi(ra[d]), shr[2*d+1]) + t1);
                B0.u[d] = f2bf(x0) | (f2bf(x1) << 16);
                float u0 = lrelu(fmaf(scr2[8+2*d],   bflo(yb[d]), shr2[8+2*d]));
                float u1 = lrelu(fmaf(scr2[8+2*d+1], bfhi(yb[d]), shr2[8+2*d+1]));
                float v0 = lrelu(fmaf(scr[8+2*d],    bflo(rb[d]), shr[8+2*d])   + u0);
                float v1 = lrelu(fmaf(scr[8+2*d+1],  bfhi(rb[d]), shr[8+2*d+1]) + u1);
                B1.u[d] = f2bf(v0) | (f2bf(v1) << 16);
            }
            u16* xrow = x2out + (size_t)(p0 + n)*64;
            *(uint4*)(xrow + q*8)      = (uint4){B0.u[0],B0.u[1],B0.u[2],B0.u[3]};
            *(uint4*)(xrow + 32 + q*8) = (uint4){B1.u[0],B1.u[1],B1.u[2],B1.u[3]};
            bf0 = B0.v; bf1 = B1.v;
        } else {
            bf0 = *(const bf8_t*)(row + q*8);
            bf1 = *(const bf8_t*)(row + 32 + q*8);
        }
        f4_t acc[4];
        #pragma unroll
        for (int mt = 0; mt < 4; ++mt){
            acc[mt] = (f4_t){0.f,0.f,0.f,0.f};
            acc[mt] = __builtin_amdgcn_mfma_f32_16x16x32_bf16(wf[mt*2+0], bf0, acc[mt], 0,0,0);
            acc[mt] = __builtin_amdgcn_mfma_f32_16x16x32_bf16(wf[mt*2+1], bf1, acc[mt], 0,0,0);
        }
        u16* orow = out + (size_t)(p0 + n)*64;
        #pragma unroll
        for (int mt = 0; mt < 4; ++mt){
            float v0 = acc[mt].x + bv[mt].x;
            float v1 = acc[mt].y + bv[mt].y;
            float v2 = acc[mt].z + bv[mt].z;
            float v3 = acc[mt].w + bv[mt].w;
            st1[mt*4+0] += v0; st2[mt*4+0] += v0*v0;
            st1[mt*4+1] += v1; st2[mt*4+1] += v1*v1;
            st1[mt*4+2] += v2; st2[mt*4+2] += v2*v2;
            st1[mt*4+3] += v3; st2[mt*4+3] += v3*v3;
            uint2 pk;
            pk.x = f2bf(v0) | (f2bf(v1) << 16);
            pk.y = f2bf(v2) | (f2bf(v3) << 16);
            *(uint2*)(orow + mt*16 + q*4) = pk;
        }
    }
    #pragma unroll
    for (int e = 0; e < 16; ++e){
        float r1 = row_sum16(st1[e]);
        float r2 = row_sum16(st2[e]);
        if (n == 15){
            const int ch = (e >> 2)*16 + q*4 + (e & 3);
            sStat[wv*128 + ch]      = r1;
            sStat[wv*128 + 64 + ch] = r2;
        }
    }
    __syncthreads();
    if (t < 128){
        float s = sStat[t] + sStat[128+t] + sStat[256+t] + sStat[384+t];
        pout[(size_t)bb*128 + t] = s;
    }
}

// ---------------------------------------------------------------------------
// Fused gather + conv_t (MFMA), bf16 gather (r3-validated).
// ---------------------------------------------------------------------------
__global__ __launch_bounds__(256,3) void gconv_mfma_kernel(const u16* __restrict__ fbf,
    const int* __restrict__ kidx, u16* __restrict__ out,
    const u16* __restrict__ wfrag, const float* __restrict__ bias,
    float* __restrict__ pout)
{
    __shared__ float sStat[4*128];
    const int t = threadIdx.x, lane = t & 63, wv = t >> 6;
    const int n = lane & 15, q = lane >> 4;
    const int bb = blockIdx.x;

    bf8_t wf[8];
    #pragma unroll
    for (int f = 0; f < 8; ++f)
        wf[f] = *(const bf8_t*)(wfrag + (f*64 + lane)*8);
    f4_t bv[4];
    #pragma unroll
    for (int mt = 0; mt < 4; ++mt)
        bv[mt] = *(const f4_t*)(bias + mt*16 + q*4);

    float st1[16], st2[16];
    #pragma unroll
    for (int e = 0; e < 16; ++e){ st1[e] = 0.0f; st2[e] = 0.0f; }

    #pragma unroll
    for (int i = 0; i < 4; ++i){
        const int p0 = bb*256 + wv*64 + i*16;
        const int p = p0 + n;
        const int b = p >> 15;
        const int idx = kidx[p];
        const u16* frow = fbf + ((size_t)b*NN + idx)*NC;
        bf8_t bf0 = *(const bf8_t*)(frow + q*8);
        bf8_t bf1 = *(const bf8_t*)(frow + 32 + q*8);
        f4_t acc[4];
        #pragma unroll
        for (int mt = 0; mt < 4; ++mt){
            acc[mt] = (f4_t){0.f,0.f,0.f,0.f};
            acc[mt] = __builtin_amdgcn_mfma_f32_16x16x32_bf16(wf[mt*2+0], bf0, acc[mt], 0,0,0);
            acc[mt] = __builtin_amdgcn_mfma_f32_16x16x32_bf16(wf[mt*2+1], bf1, acc[mt], 0,0,0);
        }
        u16* orow = out + (size_t)p*64;
        #pragma unroll
        for (int mt = 0; mt < 4; ++mt){
            float v0 = acc[mt].x + bv[mt].x;
            float v1 = acc[mt].y + bv[mt].y;
            float v2 = acc[mt].z + bv[mt].z;
            float v3 = acc[mt].w + bv[mt].w;
            st1[mt*4+0] += v0; st2[mt*4+0] += v0*v0;
            st1[mt*4+1] += v1; st2[mt*4+1] += v1*v1;
            st1[mt*4+2] += v2; st2[mt*4+2] += v2*v2;
            st1[mt*4+3] += v3; st2[mt*4+3] += v3*v3;
            uint2 pk;
            pk.x = f2bf(v0) | (f2bf(v1) << 16);
            pk.y = f2bf(v2) | (f2bf(v3) << 16);
            *(uint2*)(orow + mt*16 + q*4) = pk;
        }
    }
    #pragma unroll
    for (int e = 0; e < 16; ++e){
        float r1 = row_sum16(st1[e]);
        float r2 = row_sum16(st2[e]);
        if (n == 15){
            const int ch = (e >> 2)*16 + q*4 + (e & 3);
            sStat[wv*128 + ch]      = r1;
            sStat[wv*128 + 64 + ch] = r2;
        }
    }
    __syncthreads();
    if (t < 128){
        float s = sStat[t] + sStat[128+t] + sStat[256+t] + sStat[384+t];
        pout[(size_t)bb*128 + t] = s;
    }
}

// ---------------------------------------------------------------------------
// Final: x3 = leaky(aff(v2) + x2); out1[b,c,s] = max over 32 K-rows. (r0)
// ---------------------------------------------------------------------------
__global__ __launch_bounds__(256,2) void final_kernel(const u16* __restrict__ v2,
    const u16* __restrict__ x2, const float* __restrict__ aff,
    float* __restrict__ out1)
{
    const int t = threadIdx.x;
    const int dc = t & 31, sg = t >> 5;
    const int c0 = dc*2, c1 = c0 + 1;
    const float a0 = aff[c0], s0 = aff[64+c0];
    const float a1 = aff[c1], s1 = aff[64+c1];
    const int s = blockIdx.x*8 + sg;
    const unsigned* vp = (const unsigned*)v2;
    const unsigned* xp = (const unsigned*)x2;
    float m0 = -3.0e38f, m1 = -3.0e38f;
    #pragma unroll 8
    for (int kk = 0; kk < 32; ++kk){
        const size_t e = ((size_t)s*32 + kk)*32 + dc;
        unsigned uv = vp[e], ux = xp[e];
        m0 = fmaxf(m0, lrelu(fmaf(a0, bflo(uv), s0) + bflo(ux)));
        m1 = fmaxf(m1, lrelu(fmaf(a1, bfhi(uv), s1) + bfhi(ux)));
    }
    const int b = s >> 10, sl = s & 1023;
    out1[((size_t)b*NC + c0)*NS + sl] = m0;
    out1[((size_t)b*NC + c1)*NS + sl] = m1;
}

// ---------------------------------------------------------------------------
extern "C" void kernel_launch(void* const* d_in, const int* in_sizes, int n_in,
                              void* d_out, int out_size, void* d_ws, size_t ws_size,
                              hipStream_t stream)
{
    const float* xyz      = (const float*)d_in[0];
    const float* features = (const float*)d_in[1];
    const float* w_t    = (const float*)d_in[2];
    const float* w1_0   = (const float*)d_in[3];
    const float* w2_0   = (const float*)d_in[4];
    const float* w1_1   = (const float*)d_in[5];
    const float* w2_1   = (const float*)d_in[6];
    const float* b_t    = (const float*)d_in[7];
    const float* b1_0   = (const float*)d_in[8];
    const float* b2_0   = (const float*)d_in[9];
    const float* b1_1   = (const float*)d_in[10];
    const float* b2_1   = (const float*)d_in[11];
    const float* g_t    = (const float*)d_in[12];
    const float* g1_0   = (const float*)d_in[13];
    const float* g2_0   = (const float*)d_in[14];
    const float* g1_1   = (const float*)d_in[15];
    const float* g2_1   = (const float*)d_in[16];
    const float* beta_t  = (const float*)d_in[17];
    const float* beta1_0 = (const float*)d_in[18];
    const float* beta2_0 = (const float*)d_in[19];
    const float* beta1_1 = (const float*)d_in[20];
    const float* beta2_1 = (const float*)d_in[21];

    float* out = (float*)d_out;

    float* nxyz = (float*)d_ws;                          // 24576 f
    int*   kidx = (int*)(nxyz + 24576);                  // NP ints
    float* pT   = (float*)(kidx + NP);                   // 5 x 1024*128 partials
    float* p10  = pT  + 131072;
    float* p20  = p10 + 131072;
    float* p11  = p20 + 131072;
    float* p21  = p11 + 131072;
    float* affT  = p21 + 131072;                         // 5 x 128
    float* aff10 = affT + 128;
    float* aff20 = aff10 + 128;
    float* aff11 = aff20 + 128;
    float* aff21 = aff11 + 128;
    u16*  bwt  = (u16*)(aff21 + 128);                    // 5*4096 u16
    u16*  buf0 = bwt + 5*4096;                           // 3 x NP*64 bf16
    u16*  buf1 = buf0 + (size_t)NP*NC;
    u16*  buf2 = buf1 + (size_t)NP*NC;
    u16*  fbf  = buf2;   // bf16 features alias buf2 (dead before conv#2 writes it)

    // blocks 0..7: FPS; 8..519: feature f32->bf16; 520..524: wtrans
    fps_kernel<<<NB + 512 + 5, 256, 0, stream>>>(xyz, out, nxyz, features, fbf,
                                                 w_t, w1_0, w2_0, w1_1, w2_1, bwt);
    knn_kernel<<<NQ/4, 256, 0, stream>>>(xyz, nxyz, kidx);

    // conv_t (gather fused, bf16 gather) -> buf1, stats pT
    gconv_mfma_kernel<<<1024, 256, 0, stream>>>(fbf, kidx, buf1,
                                                bwt + 0*4096, b_t, pT);
    finalize_kernel<<<1, 1024, 0, stream>>>(pT, g_t, beta_t, affT);
    // resblock 0
    conv_mfma_kernel<1><<<1024, 256, 0, stream>>>(buf1, nullptr, buf0, nullptr,
                                                  bwt + 1*4096, b1_0, affT, nullptr, p10);
    finalize_kernel<<<1, 1024, 0, stream>>>(p10, g1_0, beta1_0, aff10);
    conv_mfma_kernel<1><<<1024, 256, 0, stream>>>(buf0, nullptr, buf2, nullptr,
                                                  bwt + 2*4096, b2_0, aff10, nullptr, p20);
    finalize_kernel<<<1, 1024, 0, stream>>>(p20, g2_0, beta2_0, aff20);
    // resblock 1 first conv with residual fused:
    //   v=buf2 (aff20), y=buf1 (affT) -> x2=buf0 (for final), out=buf1
    conv_mfma_kernel<2><<<1024, 256, 0, stream>>>(buf2, buf1, buf1, buf0,
                                                  bwt + 3*4096, b1_1, aff20, affT, p11);
    finalize_kernel<<<1, 1024, 0, stream>>>(p11, g1_1, beta1_1, aff11);
    conv_mfma_kernel<1><<<1024, 256, 0, stream>>>(buf1, nullptr, buf2, nullptr,
                                                  bwt + 4*4096, b2_1, aff11, nullptr, p21);
    finalize_kernel<<<1, 1024, 0, stream>>>(p21, g2_1, beta2_1, aff21);
    // epilogue: residual + max over K
    final_kernel<<<1024, 256, 0, stream>>>(buf2, buf0, aff21,
                                           out + (size_t)NB*3*NS);
}

// Round 8
// 902.737 us; speedup vs baseline: 1.4775x; 1.0065x over previous
//
#include <hip/hip_runtime.h>
#include <stdint.h>

#define NB 8
#define NN 4096
#define NC 64
#define NS 1024
#define NK 32
#define NQ (NB*NS)        /* 8192 queries */
#define NP (NQ*NK)        /* 262144 positions */
#define EPSBN 1e-5f

typedef unsigned long long u64;
typedef unsigned short u16;
typedef float v2f __attribute__((ext_vector_type(2)));
typedef short bf8_t __attribute__((ext_vector_type(8)));    // 8 bf16 (4 VGPRs)
typedef float f4_t __attribute__((ext_vector_type(4)));     // MFMA acc

__device__ __forceinline__ float lrelu(float x){ return x >= 0.0f ? x : 0.1f*x; }

__device__ __forceinline__ unsigned int fkey(float d){
    unsigned int fb = __float_as_uint(d);
    return (fb & 0x80000000u) ? ~fb : (fb | 0x80000000u);
}
// f32 -> bf16 RNE
__device__ __forceinline__ unsigned f2bf(float f){
    unsigned u = __float_as_uint(f);
    return (u + 0x7fffu + ((u >> 16) & 1u)) >> 16;
}
__device__ __forceinline__ float bflo(unsigned u){ return __uint_as_float(u << 16); }
__device__ __forceinline__ float bfhi(unsigned u){ return __uint_as_float(u & 0xffff0000u); }

// inclusive prefix-sum over 64 lanes (ints)
__device__ __forceinline__ int wave_incl_add(int x){
    int v = x;
    {int o=__builtin_amdgcn_update_dpp(0,v,0x111,0xf,0xf,true); v+=o;}
    {int o=__builtin_amdgcn_update_dpp(0,v,0x112,0xf,0xf,true); v+=o;}
    {int o=__builtin_amdgcn_update_dpp(0,v,0x114,0xf,0xf,true); v+=o;}
    {int o=__builtin_amdgcn_update_dpp(0,v,0x118,0xf,0xf,true); v+=o;}
    {int o=__builtin_amdgcn_update_dpp(0,v,0x142,0xa,0xf,true); v+=o;}
    {int o=__builtin_amdgcn_update_dpp(0,v,0x143,0xc,0xf,true); v+=o;}
    return v;
}
// sum within each 16-lane row; valid at lane%16==15
__device__ __forceinline__ float row_sum16(float x){
    int v = __float_as_int(x);
    {int o=__builtin_amdgcn_update_dpp(0,v,0x111,0xf,0xf,true); v=__float_as_int(__int_as_float(v)+__int_as_float(o));}
    {int o=__builtin_amdgcn_update_dpp(0,v,0x112,0xf,0xf,true); v=__float_as_int(__int_as_float(v)+__int_as_float(o));}
    {int o=__builtin_amdgcn_update_dpp(0,v,0x114,0xf,0xf,true); v=__float_as_int(__int_as_float(v)+__int_as_float(o));}
    {int o=__builtin_amdgcn_update_dpp(0,v,0x118,0xf,0xf,true); v=__float_as_int(__int_as_float(v)+__int_as_float(o));}
    return __int_as_float(v);
}
// max-reduce of a packed positive double across the wave, via DPP pairs
__device__ __forceinline__ double wave_max_d(double x){
    int lo = __double2loint(x), hi = __double2hiint(x);
    #define FPS_STG(ctl) { \
        int nl=__builtin_amdgcn_update_dpp(lo,lo,ctl,0xf,0xf,false); \
        int nh=__builtin_amdgcn_update_dpp(hi,hi,ctl,0xf,0xf,false); \
        double mx=fmax(__hiloint2double(hi,lo), __hiloint2double(nh,nl)); \
        lo=__double2loint(mx); hi=__double2hiint(mx); }
    FPS_STG(0x111) FPS_STG(0x112) FPS_STG(0x114) FPS_STG(0x118) FPS_STG(0x142) FPS_STG(0x143)
    #undef FPS_STG
    int flo = __builtin_amdgcn_readlane(lo, 63);
    int fhi = __builtin_amdgcn_readlane(hi, 63);
    return __hiloint2double(fhi, flo);
}

// ---------------------------------------------------------------------------
// FPS (r5-validated optimum, ~511 us): 1 batch/block, 8 blocks, 256 thr,
// 16 pts/thread, v2f update, SEQUENTIAL packed-f64 fmax key chain, DPP wave
// reduce, 4 LDS slots, parity double-buffer. Bit-exact: rn ops,
// ((dx2+dy2)+dz2), min, first-occurrence.
// FPS LEVER LEDGER -- all measured, do not redo:
//   fmax tree alone:        +11us (r7; chain is hidden, tree adds merge ops)
//   tree + float4 LDS:      +20us (r1; conflicts 6.6K->30K)
//   512 thr x 8 pts:        +60us (r10 prior session)
//   2 batches/block:       +427us (r6; VALU-throughput-bound per CU)
//   per-block threadfence: +650us (r4; device fences across 8 XCD L2s)
// 256thr x 8 blocks x sequential chain is the measured optimum shape.
// Piggybacks on the idle CUs (validated free):
//   blocks NB..NB+511:    features f32->bf16
//   blocks NB+512..+516:  weight A-frag pack
// ---------------------------------------------------------------------------
__global__ __launch_bounds__(256,1) void fps_kernel(const float* __restrict__ xyz,
    float* __restrict__ out0, float* __restrict__ nxyz,
    const float* __restrict__ features, u16* __restrict__ fbf,
    const float* __restrict__ w0, const float* __restrict__ w1,
    const float* __restrict__ w2, const float* __restrict__ w3,
    const float* __restrict__ w4, u16* __restrict__ bwt)
{
    if (blockIdx.x >= NB + 512){
        // weight pack (5 blocks)
        const int wb = blockIdx.x - (NB + 512);
        const float* s;
        switch (wb){
            case 0: s = w0; break; case 1: s = w1; break; case 2: s = w2; break;
            case 3: s = w3; break; default: s = w4; break;
        }
        u16* d = bwt + (size_t)wb*4096;
        for (int i = threadIdx.x; i < 4096; i += 256){
            const int f = i >> 9, lane = (i >> 3) & 63, j = i & 7;
            const int mt = f >> 1, h = f & 1;
            const int o = mt*16 + (lane & 15);
            const int c = h*32 + (lane >> 4)*8 + j;
            d[i] = (u16)f2bf(s[o*64 + c]);
        }
        return;
    }
    if (blockIdx.x >= NB){
        // feature pre-conversion: 2M floats -> bf16
        const int cb = blockIdx.x - NB;
        const float4* src = (const float4*)features;
        uint2* dst = (uint2*)fbf;
        for (int i = cb*256 + threadIdx.x; i < NB*NN*NC/4; i += 512*256){
            float4 v = src[i];
            uint2 pk;
            pk.x = f2bf(v.x) | (f2bf(v.y) << 16);
            pk.y = f2bf(v.z) | (f2bf(v.w) << 16);
            dst[i] = pk;
        }
        return;
    }
    __shared__ float sX[NN], sY[NN], sZ[NN];
    __shared__ double slots[2][4];
    __shared__ int sFar[NS];
    const int b = blockIdx.x, t = threadIdx.x;
    const int lane = t & 63, wv = t >> 6;
    const float* base = xyz + (size_t)b*NN*3;
    for (int i = t; i < NN; i += 256){
        const float* pp = base + 3*i;
        sX[i] = pp[0]; sY[i] = pp[1]; sZ[i] = pp[2];
    }
    __syncthreads();
    v2f PX[8], PY[8], PZ[8], D[8];
    int LO[16];
    const int pb = t*16;
    #pragma unroll
    for (int j = 0; j < 8; ++j){
        PX[j] = (v2f){ sX[pb+2*j], sX[pb+2*j+1] };
        PY[j] = (v2f){ sY[pb+2*j], sY[pb+2*j+1] };
        PZ[j] = (v2f){ sZ[pb+2*j], sZ[pb+2*j+1] };
        D[j]  = (v2f){ 1e10f, 1e10f };
    }
    #pragma unroll
    for (int j = 0; j < 16; ++j) LO[j] = (int)(~(unsigned)(pb + j));
    int far = 0;
    float cx = sX[0], cy = sY[0], cz = sZ[0];
    for (int s = 0; s < NS; ++s){
        if (t == 255) sFar[s] = far;
        double best;
        {
            #pragma clang fp contract(off)
            v2f cx2 = (v2f){cx, cx}, cy2 = (v2f){cy, cy}, cz2 = (v2f){cz, cz};
            best = -1.0;
            #pragma unroll
            for (int j = 0; j < 8; ++j){
                v2f dx = PX[j] - cx2;
                v2f dy = PY[j] - cy2;
                v2f dz = PZ[j] - cz2;
                v2f dd = (dx*dx + dy*dy) + dz*dz;
                v2f nd = __builtin_elementwise_min(D[j], dd);
                D[j] = nd;
                best = fmax(best, __hiloint2double(__float_as_int(nd.x), LO[2*j]));
                best = fmax(best, __hiloint2double(__float_as_int(nd.y), LO[2*j+1]));
            }
        }
        double wb = wave_max_d(best);
        const int par = s & 1;
        if (lane == 0) slots[par][wv] = wb;
        __syncthreads();
        double s0 = slots[par][0], s1 = slots[par][1];
        double s2 = slots[par][2], s3 = slots[par][3];
        double mm = fmax(fmax(s0, s1), fmax(s2, s3));
        far = (int)(~(unsigned)__double2loint(mm));
        cx = sX[far]; cy = sY[far]; cz = sZ[far];
    }
    __syncthreads();
    for (int s = t; s < NS; s += 256){
        const int f = sFar[s];
        const float x = sX[f], y = sY[f], z = sZ[f];
        float* npq = nxyz + ((size_t)b*NS + s)*3;
        npq[0]=x; npq[1]=y; npq[2]=z;
        out0[(b*3+0)*NS+s]=x; out0[(b*3+1)*NS+s]=y; out0[(b*3+2)*NS+s]=z;
    }
}

// ---------------------------------------------------------------------------
// KNN (unchanged): exact 32nd-smallest via bitwise binary search on fkey.
// ---------------------------------------------------------------------------
__global__ __launch_bounds__(256,2) void knn_kernel(const float* __restrict__ xyz,
                                                    const float* __restrict__ nxyz,
                                                    int* __restrict__ kidx)
{
    const int t = threadIdx.x, lane = t & 63, w = t >> 6;
    const int q = blockIdx.x*4 + w;
    const int b = q >> 10;
    const float* base = xyz + (size_t)b*NN*3;
    const float* qp = nxyz + (size_t)q*3;
    const float qx = qp[0], qy = qp[1], qz = qp[2];
    const float qsq = __fadd_rn(__fadd_rn(__fmul_rn(qx,qx),__fmul_rn(qy,qy)),__fmul_rn(qz,qz));

    unsigned int key[64];
    #pragma unroll
    for (int i = 0; i < 64; ++i){
        const int idx = (i<<6) + lane;
        const float* pp = base + 3*idx;
        float x = pp[0], y = pp[1], z = pp[2];
        float dot = __fadd_rn(__fadd_rn(__fmul_rn(qx,x),__fmul_rn(qy,y)),__fmul_rn(qz,z));
        float psq = __fadd_rn(__fadd_rn(__fmul_rn(x,x),__fmul_rn(y,y)),__fmul_rn(z,z));
        float d = __fadd_rn(__fadd_rn(__fmul_rn(-2.0f,dot),qsq),psq);
        key[i] = fkey(d);
    }
    unsigned int pref = 0; int need = 32;
    for (int bit = 31; bit >= 0; --bit){
        const unsigned int bound = 1u << bit;
        int c = 0;
        #pragma unroll
        for (int i = 0; i < 64; ++i) c += ((key[i] ^ pref) < bound) ? 1 : 0;
        int tot = __builtin_amdgcn_readlane(wave_incl_add(c), 63);
        if (tot < need){ need -= tot; pref |= bound; }
    }
    const unsigned int T = pref;
    int cl = 0;
    #pragma unroll
    for (int i = 0; i < 64; ++i) cl += (key[i] < T) ? 1 : 0;
    int incl_cl = wave_incl_add(cl);
    int clx = incl_cl - cl;
    int tiebase = __builtin_amdgcn_readlane(incl_cl, 63);
    int* oq = kidx + (size_t)q*NK;
    int pos = clx;
    #pragma unroll
    for (int i = 0; i < 64; ++i){
        if (key[i] < T){ oq[pos] = (i<<6) + lane; ++pos; }
    }
    int tcount = 0;
    for (int i = 0; i < 64 && tcount < need; ++i){
        u64 m = __ballot(key[i] == T);
        int myrank = (int)__popcll(m & ((1ull << lane) - 1ull));
        if ((key[i] == T) && (tcount + myrank < need))
            oq[tiebase + tcount + myrank] = (i<<6) + lane;
        tcount += (int)__popcll(m);
    }
}

// ---------------------------------------------------------------------------
// Fast BN finalize (r0/r3-validated, measured-cheap): 1 block x 1024 thr;
// 8-way row split + LDS tree. KEEP AS SEPARATE LAUNCHES (r4 lesson:
// per-block device fences cost +650us; r2 lesson: atomic stats +46-58us).
// ---------------------------------------------------------------------------
__global__ __launch_bounds__(1024) void finalize_kernel(const float* __restrict__ pin,
    const float* __restrict__ g, const float* __restrict__ beta, float* __restrict__ aff)
{
    __shared__ float l1[1024];
    const int t = threadIdx.x;
    const int stat = t & 127, seg = t >> 7;
    float S = 0.0f;
    #pragma unroll 8
    for (int r = seg*128; r < seg*128 + 128; ++r) S += pin[r*128 + stat];
    l1[t] = S;
    __syncthreads();
    if (t < 128){
        float s = l1[t] + l1[128+t] + l1[256+t] + l1[384+t]
                + l1[512+t] + l1[640+t] + l1[768+t] + l1[896+t];
        l1[t] = s;
    }
    __syncthreads();
    if (t < 64){
        float mean = l1[t] * (1.0f/(float)NP);
        float var  = fmaxf(l1[64+t] * (1.0f/(float)NP) - mean*mean, 0.0f);
        float sc = g[t] * rsqrtf(var + EPSBN);
        aff[t]    = sc;
        aff[64+t] = beta[t] - mean*sc;
    }
}

// ---------------------------------------------------------------------------
// MFMA conv core (r3 inner loop, byte-identical for ACT=0/1). ACT=2
// (r4/r5-validated): fused residual -- input = lrelu(affV(in) +
// lrelu(affY(in2))); packed x2 stored to x2out (for final_kernel) AND used
// as the MFMA operand. In-place out==in2 is safe: each row is owned by one
// wave; reads complete before its writes. Stats: non-atomic partials.
// ---------------------------------------------------------------------------
template<int ACT>
__global__ __launch_bounds__(256, (ACT==2)?2:3) void conv_mfma_kernel(
    const u16* __restrict__ in, const u16* __restrict__ in2,
    u16* __restrict__ out, u16* __restrict__ x2out,
    const u16* __restrict__ wfrag, const float* __restrict__ bias,
    const float* __restrict__ aff, const float* __restrict__ aff2,
    float* __restrict__ pout)
{
    __shared__ float sStat[4*128];
    const int t = threadIdx.x, lane = t & 63, wv = t >> 6;
    const int n = lane & 15, q = lane >> 4;
    const int bb = blockIdx.x;

    float scr[16], shr[16];
    float scr2[16], shr2[16];
    if (ACT){
        #pragma unroll
        for (int h = 0; h < 2; ++h){
            float4 a0 = *(const float4*)(aff + h*32 + q*8);
            float4 a1 = *(const float4*)(aff + h*32 + q*8 + 4);
            float4 b0 = *(const float4*)(aff + 64 + h*32 + q*8);
            float4 b1 = *(const float4*)(aff + 64 + h*32 + q*8 + 4);
            scr[h*8+0]=a0.x; scr[h*8+1]=a0.y; scr[h*8+2]=a0.z; scr[h*8+3]=a0.w;
            scr[h*8+4]=a1.x; scr[h*8+5]=a1.y; scr[h*8+6]=a1.z; scr[h*8+7]=a1.w;
            shr[h*8+0]=b0.x; shr[h*8+1]=b0.y; shr[h*8+2]=b0.z; shr[h*8+3]=b0.w;
            shr[h*8+4]=b1.x; shr[h*8+5]=b1.y; shr[h*8+6]=b1.z; shr[h*8+7]=b1.w;
        }
        if (ACT == 2){
            #pragma unroll
            for (int h = 0; h < 2; ++h){
                float4 a0 = *(const float4*)(aff2 + h*32 + q*8);
                float4 a1 = *(const float4*)(aff2 + h*32 + q*8 + 4);
                float4 b0 = *(const float4*)(aff2 + 64 + h*32 + q*8);
                float4 b1 = *(const float4*)(aff2 + 64 + h*32 + q*8 + 4);
                scr2[h*8+0]=a0.x; scr2[h*8+1]=a0.y; scr2[h*8+2]=a0.z; scr2[h*8+3]=a0.w;
                scr2[h*8+4]=a1.x; scr2[h*8+5]=a1.y; scr2[h*8+6]=a1.z; scr2[h*8+7]=a1.w;
                shr2[h*8+0]=b0.x; shr2[h*8+1]=b0.y; shr2[h*8+2]=b0.z; shr2[h*8+3]=b0.w;
                shr2[h*8+4]=b1.x; shr2[h*8+5]=b1.y; shr2[h*8+6]=b1.z; shr2[h*8+7]=b1.w;
            }
        }
    }
    bf8_t wf[8];
    #pragma unroll
    for (int f = 0; f < 8; ++f)
        wf[f] = *(const bf8_t*)(wfrag + (f*64 + lane)*8);
    f4_t bv[4];
    #pragma unroll
    for (int mt = 0; mt < 4; ++mt)
        bv[mt] = *(const f4_t*)(bias + mt*16 + q*4);

    float st1[16], st2[16];
    #pragma unroll
    for (int e = 0; e < 16; ++e){ st1[e] = 0.0f; st2[e] = 0.0f; }

    #pragma unroll
    for (int i = 0; i < 4; ++i){
        const int p0 = bb*256 + wv*64 + i*16;
        const u16* row = in + (size_t)(p0 + n)*64;
        bf8_t bf0, bf1;
        union { unsigned u[4]; bf8_t v; } B0, B1;
        if (ACT == 1){
            uint4 r0 = *(const uint4*)(row + q*8);
            uint4 r1 = *(const uint4*)(row + 32 + q*8);
            const unsigned ra[4] = {r0.x, r0.y, r0.z, r0.w};
            const unsigned rb[4] = {r1.x, r1.y, r1.z, r1.w};
            #pragma unroll
            for (int d = 0; d < 4; ++d){
                float x0 = bflo(ra[d]), x1 = bfhi(ra[d]);
                float y0 = fmaf(scr[2*d],   x0, shr[2*d]);   y0 = lrelu(y0);
                float y1 = fmaf(scr[2*d+1], x1, shr[2*d+1]); y1 = lrelu(y1);
                B0.u[d] = f2bf(y0) | (f2bf(y1) << 16);
                float z0 = bflo(rb[d]), z1 = bfhi(rb[d]);
                float w0 = fmaf(scr[8+2*d],   z0, shr[8+2*d]);   w0 = lrelu(w0);
                float w1 = fmaf(scr[8+2*d+1], z1, shr[8+2*d+1]); w1 = lrelu(w1);
                B1.u[d] = f2bf(w0) | (f2bf(w1) << 16);
            }
            bf0 = B0.v; bf1 = B1.v;
        } else if (ACT == 2){ // fused residual (exact resid_kernel arithmetic)
            const u16* yrow = in2 + (size_t)(p0 + n)*64;
            uint4 r0 = *(const uint4*)(row + q*8);
            uint4 r1 = *(const uint4*)(row + 32 + q*8);
            uint4 s0 = *(const uint4*)(yrow + q*8);
            uint4 s1 = *(const uint4*)(yrow + 32 + q*8);
            const unsigned ra[4] = {r0.x, r0.y, r0.z, r0.w};
            const unsigned rb[4] = {r1.x, r1.y, r1.z, r1.w};
            const unsigned ya[4] = {s0.x, s0.y, s0.z, s0.w};
            const unsigned yb[4] = {s1.x, s1.y, s1.z, s1.w};
            #pragma unroll
            for (int d = 0; d < 4; ++d){
                float t0 = lrelu(fmaf(scr2[2*d],   bflo(ya[d]), shr2[2*d]));
                float t1 = lrelu(fmaf(scr2[2*d+1], bfhi(ya[d]), shr2[2*d+1]));
                float x0 = lrelu(fmaf(scr[2*d],    bflo(ra[d]), shr[2*d])   + t0);
                float x1 = lrelu(fmaf(scr[2*d+1],  bfhi(ra[d]), shr[2*d+1]) + t1);
                B0.u[d] = f2bf(x0) | (f2bf(x1) << 16);
                float u0 = lrelu(fmaf(scr2[8+2*d],   bflo(yb[d]), shr2[8+2*d]));
                float u1 = lrelu(fmaf(scr2[8+2*d+1], bfhi(yb[d]), shr2[8+2*d+1]));
                float v0 = lrelu(fmaf(scr[8+2*d],    bflo(rb[d]), shr[8+2*d])   + u0);
                float v1 = lrelu(fmaf(scr[8+2*d+1],  bfhi(rb[d]), shr[8+2*d+1]) + u1);
                B1.u[d] = f2bf(v0) | (f2bf(v1) << 16);
            }
            u16* xrow = x2out + (size_t)(p0 + n)*64;
            *(uint4*)(xrow + q*8)      = (uint4){B0.u[0],B0.u[1],B0.u[2],B0.u[3]};
            *(uint4*)(xrow + 32 + q*8) = (uint4){B1.u[0],B1.u[1],B1.u[2],B1.u[3]};
            bf0 = B0.v; bf1 = B1.v;
        } else {
            bf0 = *(const bf8_t*)(row + q*8);
            bf1 = *(const bf8_t*)(row + 32 + q*8);
        }
        f4_t acc[4];
        #pragma unroll
        for (int mt = 0; mt < 4; ++mt){
            acc[mt] = (f4_t){0.f,0.f,0.f,0.f};
            acc[mt] = __builtin_amdgcn_mfma_f32_16x16x32_bf16(wf[mt*2+0], bf0, acc[mt], 0,0,0);
            acc[mt] = __builtin_amdgcn_mfma_f32_16x16x32_bf16(wf[mt*2+1], bf1, acc[mt], 0,0,0);
        }
        u16* orow = out + (size_t)(p0 + n)*64;
        #pragma unroll
        for (int mt = 0; mt < 4; ++mt){
            float v0 = acc[mt].x + bv[mt].x;
            float v1 = acc[mt].y + bv[mt].y;
            float v2 = acc[mt].z + bv[mt].z;
            float v3 = acc[mt].w + bv[mt].w;
            st1[mt*4+0] += v0; st2[mt*4+0] += v0*v0;
            st1[mt*4+1] += v1; st2[mt*4+1] += v1*v1;
            st1[mt*4+2] += v2; st2[mt*4+2] += v2*v2;
            st1[mt*4+3] += v3; st2[mt*4+3] += v3*v3;
            uint2 pk;
            pk.x = f2bf(v0) | (f2bf(v1) << 16);
            pk.y = f2bf(v2) | (f2bf(v3) << 16);
            *(uint2*)(orow + mt*16 + q*4) = pk;
        }
    }
    #pragma unroll
    for (int e = 0; e < 16; ++e){
        float r1 = row_sum16(st1[e]);
        float r2 = row_sum16(st2[e]);
        if (n == 15){
            const int ch = (e >> 2)*16 + q*4 + (e & 3);
            sStat[wv*128 + ch]      = r1;
            sStat[wv*128 + 64 + ch] = r2;
        }
    }
    __syncthreads();
    if (t < 128){
        float s = sStat[t] + sStat[128+t] + sStat[256+t] + sStat[384+t];
        pout[(size_t)bb*128 + t] = s;
    }
}

// ---------------------------------------------------------------------------
// Fused gather + conv_t (MFMA), bf16 gather (r3-validated).
// ---------------------------------------------------------------------------
__global__ __launch_bounds__(256,3) void gconv_mfma_kernel(const u16* __restrict__ fbf,
    const int* __restrict__ kidx, u16* __restrict__ out,
    const u16* __restrict__ wfrag, const float* __restrict__ bias,
    float* __restrict__ pout)
{
    __shared__ float sStat[4*128];
    const int t = threadIdx.x, lane = t & 63, wv = t >> 6;
    const int n = lane & 15, q = lane >> 4;
    const int bb = blockIdx.x;

    bf8_t wf[8];
    #pragma unroll
    for (int f = 0; f < 8; ++f)
        wf[f] = *(const bf8_t*)(wfrag + (f*64 + lane)*8);
    f4_t bv[4];
    #pragma unroll
    for (int mt = 0; mt < 4; ++mt)
        bv[mt] = *(const f4_t*)(bias + mt*16 + q*4);

    float st1[16], st2[16];
    #pragma unroll
    for (int e = 0; e < 16; ++e){ st1[e] = 0.0f; st2[e] = 0.0f; }

    #pragma unroll
    for (int i = 0; i < 4; ++i){
        const int p0 = bb*256 + wv*64 + i*16;
        const int p = p0 + n;
        const int b = p >> 15;
        const int idx = kidx[p];
        const u16* frow = fbf + ((size_t)b*NN + idx)*NC;
        bf8_t bf0 = *(const bf8_t*)(frow + q*8);
        bf8_t bf1 = *(const bf8_t*)(frow + 32 + q*8);
        f4_t acc[4];
        #pragma unroll
        for (int mt = 0; mt < 4; ++mt){
            acc[mt] = (f4_t){0.f,0.f,0.f,0.f};
            acc[mt] = __builtin_amdgcn_mfma_f32_16x16x32_bf16(wf[mt*2+0], bf0, acc[mt], 0,0,0);
            acc[mt] = __builtin_amdgcn_mfma_f32_16x16x32_bf16(wf[mt*2+1], bf1, acc[mt], 0,0,0);
        }
        u16* orow = out + (size_t)p*64;
        #pragma unroll
        for (int mt = 0; mt < 4; ++mt){
            float v0 = acc[mt].x + bv[mt].x;
            float v1 = acc[mt].y + bv[mt].y;
            float v2 = acc[mt].z + bv[mt].z;
            float v3 = acc[mt].w + bv[mt].w;
            st1[mt*4+0] += v0; st2[mt*4+0] += v0*v0;
            st1[mt*4+1] += v1; st2[mt*4+1] += v1*v1;
            st1[mt*4+2] += v2; st2[mt*4+2] += v2*v2;
            st1[mt*4+3] += v3; st2[mt*4+3] += v3*v3;
            uint2 pk;
            pk.x = f2bf(v0) | (f2bf(v1) << 16);
            pk.y = f2bf(v2) | (f2bf(v3) << 16);
            *(uint2*)(orow + mt*16 + q*4) = pk;
        }
    }
    #pragma unroll
    for (int e = 0; e < 16; ++e){
        float r1 = row_sum16(st1[e]);
        float r2 = row_sum16(st2[e]);
        if (n == 15){
            const int ch = (e >> 2)*16 + q*4 + (e & 3);
            sStat[wv*128 + ch]      = r1;
            sStat[wv*128 + 64 + ch] = r2;
        }
    }
    __syncthreads();
    if (t < 128){
        float s = sStat[t] + sStat[128+t] + sStat[256+t] + sStat[384+t];
        pout[(size_t)bb*128 + t] = s;
    }
}

// ---------------------------------------------------------------------------
// Final: x3 = leaky(aff(v2) + x2); out1[b,c,s] = max over 32 K-rows. (r0)
// ---------------------------------------------------------------------------
__global__ __launch_bounds__(256,2) void final_kernel(const u16* __restrict__ v2,
    const u16* __restrict__ x2, const float* __restrict__ aff,
    float* __restrict__ out1)
{
    const int t = threadIdx.x;
    const int dc = t & 31, sg = t >> 5;
    const int c0 = dc*2, c1 = c0 + 1;
    const float a0 = aff[c0], s0 = aff[64+c0];
    const float a1 = aff[c1], s1 = aff[64+c1];
    const int s = blockIdx.x*8 + sg;
    const unsigned* vp = (const unsigned*)v2;
    const unsigned* xp = (const unsigned*)x2;
    float m0 = -3.0e38f, m1 = -3.0e38f;
    #pragma unroll 8
    for (int kk = 0; kk < 32; ++kk){
        const size_t e = ((size_t)s*32 + kk)*32 + dc;
        unsigned uv = vp[e], ux = xp[e];
        m0 = fmaxf(m0, lrelu(fmaf(a0, bflo(uv), s0) + bflo(ux)));
        m1 = fmaxf(m1, lrelu(fmaf(a1, bfhi(uv), s1) + bfhi(ux)));
    }
    const int b = s >> 10, sl = s & 1023;
    out1[((size_t)b*NC + c0)*NS + sl] = m0;
    out1[((size_t)b*NC + c1)*NS + sl] = m1;
}

// ---------------------------------------------------------------------------
extern "C" void kernel_launch(void* const* d_in, const int* in_sizes, int n_in,
                              void* d_out, int out_size, void* d_ws, size_t ws_size,
                              hipStream_t stream)
{
    const float* xyz      = (const float*)d_in[0];
    const float* features = (const float*)d_in[1];
    const float* w_t    = (const float*)d_in[2];
    const float* w1_0   = (const float*)d_in[3];
    const float* w2_0   = (const float*)d_in[4];
    const float* w1_1   = (const float*)d_in[5];
    const float* w2_1   = (const float*)d_in[6];
    const float* b_t    = (const float*)d_in[7];
    const float* b1_0   = (const float*)d_in[8];
    const float* b2_0   = (const float*)d_in[9];
    const float* b1_1   = (const float*)d_in[10];
    const float* b2_1   = (const float*)d_in[11];
    const float* g_t    = (const float*)d_in[12];
    const float* g1_0   = (const float*)d_in[13];
    const float* g2_0   = (const float*)d_in[14];
    const float* g1_1   = (const float*)d_in[15];
    const float* g2_1   = (const float*)d_in[16];
    const float* beta_t  = (const float*)d_in[17];
    const float* beta1_0 = (const float*)d_in[18];
    const float* beta2_0 = (const float*)d_in[19];
    const float* beta1_1 = (const float*)d_in[20];
    const float* beta2_1 = (const float*)d_in[21];

    float* out = (float*)d_out;

    float* nxyz = (float*)d_ws;                          // 24576 f
    int*   kidx = (int*)(nxyz + 24576);                  // NP ints
    float* pT   = (float*)(kidx + NP);                   // 5 x 1024*128 partials
    float* p10  = pT  + 131072;
    float* p20  = p10 + 131072;
    float* p11  = p20 + 131072;
    float* p21  = p11 + 131072;
    float* affT  = p21 + 131072;                         // 5 x 128
    float* aff10 = affT + 128;
    float* aff20 = aff10 + 128;
    float* aff11 = aff20 + 128;
    float* aff21 = aff11 + 128;
    u16*  bwt  = (u16*)(aff21 + 128);                    // 5*4096 u16
    u16*  buf0 = bwt + 5*4096;                           // 3 x NP*64 bf16
    u16*  buf1 = buf0 + (size_t)NP*NC;
    u16*  buf2 = buf1 + (size_t)NP*NC;
    u16*  fbf  = buf2;   // bf16 features alias buf2 (dead before conv#2 writes it)

    // blocks 0..7: FPS; 8..519: feature f32->bf16; 520..524: wtrans
    fps_kernel<<<NB + 512 + 5, 256, 0, stream>>>(xyz, out, nxyz, features, fbf,
                                                 w_t, w1_0, w2_0, w1_1, w2_1, bwt);
    knn_kernel<<<NQ/4, 256, 0, stream>>>(xyz, nxyz, kidx);

    // conv_t (gather fused, bf16 gather) -> buf1, stats pT
    gconv_mfma_kernel<<<1024, 256, 0, stream>>>(fbf, kidx, buf1,
                                                bwt + 0*4096, b_t, pT);
    finalize_kernel<<<1, 1024, 0, stream>>>(pT, g_t, beta_t, affT);
    // resblock 0
    conv_mfma_kernel<1><<<1024, 256, 0, stream>>>(buf1, nullptr, buf0, nullptr,
                                                  bwt + 1*4096, b1_0, affT, nullptr, p10);
    finalize_kernel<<<1, 1024, 0, stream>>>(p10, g1_0, beta1_0, aff10);
    conv_mfma_kernel<1><<<1024, 256, 0, stream>>>(buf0, nullptr, buf2, nullptr,
                                                  bwt + 2*4096, b2_0, aff10, nullptr, p20);
    finalize_kernel<<<1, 1024, 0, stream>>>(p20, g2_0, beta2_0, aff20);
    // resblock 1 first conv with residual fused:
    //   v=buf2 (aff20), y=buf1 (affT) -> x2=buf0 (for final), out=buf1
    conv_mfma_kernel<2><<<1024, 256, 0, stream>>>(buf2, buf1, buf1, buf0,
                                                  bwt + 3*4096, b1_1, aff20, affT, p11);
    finalize_kernel<<<1, 1024, 0, stream>>>(p11, g1_1, beta1_1, aff11);
    conv_mfma_kernel<1><<<1024, 256, 0, stream>>>(buf1, nullptr, buf2, nullptr,
                                                  bwt + 4*4096, b2_1, aff11, nullptr, p21);
    finalize_kernel<<<1, 1024, 0, stream>>>(p21, g2_1, beta2_1, aff21);
    // epilogue: residual + max over K
    final_kernel<<<1024, 256, 0, stream>>>(buf2, buf0, aff21,
                                           out + (size_t)NB*3*NS);
}